// Round 11
// baseline (2751.184 us; speedup 1.0000x reference)
//
#include <hip/hip_runtime.h>
#include <stdint.h>

// ---------------------------------------------------------------------------
// Round 11: k_mfma_nt2 = 128x128 tile (48 MFMA vs 16 ds_read/chunk, matrix-
// pipe dominant) + XCD n-swizzle (npad=24 => same-n m-blocks on one XCD, B
// fetched once) for deform/wxf/wx/s1 GEMMs. s2 keeps 128x64. Rest as r10.
// ---------------------------------------------------------------------------

typedef unsigned short ushort_t;
typedef __attribute__((ext_vector_type(8))) short bf16x8;
typedef __attribute__((ext_vector_type(4))) float f32x4;

#define BN 2
#define HH 48
#define WWD 48
#define HW 2304

__device__ __forceinline__ float b2f(ushort_t h) {
  union { uint32_t u; float f; } v; v.u = ((uint32_t)h) << 16; return v.f;
}
__device__ __forceinline__ ushort_t f2b(float f) {
  union { float f; uint32_t u; } v; v.f = f;
  uint32_t u = v.u;
  uint32_t r = (u + 0x7fffu + ((u >> 16) & 1u)) >> 16;
  return (ushort_t)r;
}
__device__ __forceinline__ void split_bf(float v, ushort_t& hi, ushort_t& lo) {
  hi = f2b(v);
  lo = f2b(v - b2f(hi));
}

// ---------------- elementwise / packing kernels ----------------------------

__global__ void k_split_xy(const float* __restrict__ in, float* __restrict__ xf,
                           float* __restrict__ yf) {
  int idx = blockIdx.x * blockDim.x + threadIdx.x;
  const int tot = BN * 256 * HW;
  if (idx >= tot) return;
  int b = idx / (256 * HW);
  int r = idx - b * (256 * HW);
  xf[idx] = in[(size_t)(2 * b) * (256 * HW) + r];
  yf[idx] = in[(size_t)(2 * b + 1) * (256 * HW) + r];
}

__global__ void k_concat512(const float* __restrict__ a, const float* __restrict__ c2,
                            float* __restrict__ feat) {
  int idx = blockIdx.x * blockDim.x + threadIdx.x;
  const int tot = BN * 512 * HW;
  if (idx >= tot) return;
  int b = idx / (512 * HW);
  int r = idx - b * (512 * HW);
  int c = r / HW;
  int n = r - c * HW;
  feat[idx] = (c < 256) ? a[(b * 256 + c) * HW + n]
                        : c2[(b * 256 + (c - 256)) * HW + n];
}

__global__ void k_relu(float* __restrict__ p, int n) {
  int idx = blockIdx.x * blockDim.x + threadIdx.x;
  if (idx < n) p[idx] = fmaxf(p[idx], 0.f);
}

__global__ void k_mean(const float* __restrict__ src, float* __restrict__ dst,
                       int M, int N) {
  int idx = blockIdx.x * blockDim.x + threadIdx.x;
  if (idx >= BN * M) return;
  const float* p = src + (size_t)idx * N;
  float s = 0.f;
  for (int i = 0; i < N; ++i) s += p[i];
  dst[idx] = s / (float)N;
}

__global__ void k_w2b(const float* __restrict__ w, ushort_t* __restrict__ ohi,
                      ushort_t* __restrict__ olo, int n) {
  int idx = blockIdx.x * blockDim.x + threadIdx.x;
  if (idx < n) split_bf(w[idx], ohi[idx], olo[idx]);
}

__global__ void k_w2b_pad(const float* __restrict__ w, ushort_t* __restrict__ ohi,
                          ushort_t* __restrict__ olo, int M, int K, int Kpad) {
  int idx = blockIdx.x * blockDim.x + threadIdx.x;
  if (idx >= M * Kpad) return;
  int m = idx / Kpad, k = idx - m * Kpad;
  float v = (k < K) ? w[(size_t)m * K + k] : 0.f;
  split_bf(v, ohi[idx], olo[idx]);
}

__global__ void k_w2b_fw(const float* __restrict__ w, const float* __restrict__ wb,
                         const float* __restrict__ fw, ushort_t* __restrict__ ohi,
                         ushort_t* __restrict__ olo, int M, int K) {
  int idx = blockIdx.x * blockDim.x + threadIdx.x;
  int tot = BN * M * K;
  if (idx >= tot) return;
  int b = idx / (M * K);
  int r = idx - b * (M * K);
  int m = r / K;
  split_bf(fw[b * M + m] * w[r] + wb[r], ohi[idx], olo[idx]);
}

__global__ void k_w2b_fw_pad(const float* __restrict__ w, const float* __restrict__ wb,
                             const float* __restrict__ fw, ushort_t* __restrict__ ohi,
                             ushort_t* __restrict__ olo, int M, int K, int Kpad) {
  int idx = blockIdx.x * blockDim.x + threadIdx.x;
  int tot = BN * M * Kpad;
  if (idx >= tot) return;
  int b = idx / (M * Kpad);
  int r = idx - b * (M * Kpad);
  int m = r / Kpad;
  int k = r - m * Kpad;
  float v = 0.f;
  if (k < K) v = fw[b * M + m] * w[(size_t)m * K + k] + wb[(size_t)m * K + k];
  split_bf(v, ohi[idx], olo[idx]);
}

__global__ void k_correlation(const float* __restrict__ R0,
                              const float* __restrict__ T0, int aslot,
                              float* __restrict__ featw) {
  int idx = blockIdx.x * blockDim.x + threadIdx.x;
  const int tot = BN * 49 * HW;
  if (idx >= tot) return;
  int n = idx % HW;
  int t = idx / HW;
  int d = t % 49;
  int b = t / 49;
  int dyi = d / 7, dxi = d - dyi * 7;
  int dy = 2 * (dyi - 3), dx = 2 * (dxi - 3);
  int h = n / WWD, w = n - h * WWD;
  int hb = h + dy, wb = w + dx;
  float s = 0.f;
  if (hb >= 0 && hb < HH && wb >= 0 && wb < WWD) {
    const float* ap = R0 + ((size_t)(b * 2 + aslot) * 64) * HW + n;
    const float* bp = T0 + ((size_t)(b * 2 + 1) * 64) * HW + hb * WWD + wb;
#pragma unroll 8
    for (int c = 0; c < 64; ++c) s += ap[(size_t)c * HW] * bp[(size_t)c * HW];
  }
  featw[((size_t)b * 177 + d) * HW + n] = s * (1.f / 64.f);
}

__global__ void k_pack_enc(const float* __restrict__ xe, const float* __restrict__ ye,
                           float* __restrict__ featw) {
  int idx = blockIdx.x * blockDim.x + threadIdx.x;
  const int tot = BN * 64 * HW;
  if (idx >= tot) return;
  int b = idx / (64 * HW);
  int r = idx - b * (64 * HW);
  featw[((size_t)b * 177 + 49) * HW + r] = xe[idx];
  featw[((size_t)b * 177 + 113) * HW + r] = ye[idx];
}

// ---------------- im2col v2 (3x3 pad1 on 48x48, deform/zero) ---------------
template <int ZERO>
__global__ __launch_bounds__(256) void k_im2col2(
    const float* __restrict__ src, const float* __restrict__ off,
    ushort_t* __restrict__ dhi, ushort_t* __restrict__ dlo, int C) {
  __shared__ ushort_t LH[64][152];
  __shared__ ushort_t LL[64][152];
  const int b = blockIdx.z;
  const int t = threadIdx.x;
  const int nloc = t >> 2;
  const int csub = t & 3;
  const int n = blockIdx.x * 64 + nloc;
  const int c0 = blockIdx.y * 16 + csub * 4;
  const int K = C * 9;
  const int h = n / WWD, w = n - (n / WWD) * WWD;
  const float* sp = src + (size_t)b * C * HW;

  float wgt[9][4];
  int sid[9][4];
  if (ZERO) {
#pragma unroll
    for (int q = 0; q < 9; ++q) {
      int ki = q / 3, kj = q - (q / 3) * 3;
      int y = h - 1 + ki, x = w - 1 + kj;
      bool v = (y >= 0 && y < HH && x >= 0 && x < WWD);
      sid[q][0] = v ? y * WWD + x : 0;
      wgt[q][0] = v ? 1.f : 0.f;
    }
  } else {
#pragma unroll
    for (int q = 0; q < 9; ++q) {
      int ki = q / 3, kj = q - (q / 3) * 3;
      float dy = off[((size_t)(b * 9 + q) * 2 + 0) * HW + n];
      float dx = off[((size_t)(b * 9 + q) * 2 + 1) * HW + n];
      float py = (float)(h - 1 + ki) + dy;
      float px = (float)(w - 1 + kj) + dx;
      float fy = floorf(py), fx = floorf(px);
      float ay = py - fy, ax = px - fx;
      int y0 = (int)fy, x0 = (int)fx;
      int y1 = y0 + 1, x1 = x0 + 1;
      float w00 = (1.f - ay) * (1.f - ax), w01 = (1.f - ay) * ax;
      float w10 = ay * (1.f - ax), w11 = ay * ax;
      bool vy0 = (y0 >= 0 && y0 < HH), vy1 = (y1 >= 0 && y1 < HH);
      bool vx0 = (x0 >= 0 && x0 < WWD), vx1 = (x1 >= 0 && x1 < WWD);
      int cy0 = min(max(y0, 0), HH - 1), cy1 = min(max(y1, 0), HH - 1);
      int cx0 = min(max(x0, 0), WWD - 1), cx1 = min(max(x1, 0), WWD - 1);
      sid[q][0] = cy0 * WWD + cx0;
      sid[q][1] = cy0 * WWD + cx1;
      sid[q][2] = cy1 * WWD + cx0;
      sid[q][3] = cy1 * WWD + cx1;
      wgt[q][0] = (vy0 && vx0) ? w00 : 0.f;
      wgt[q][1] = (vy0 && vx1) ? w01 : 0.f;
      wgt[q][2] = (vy1 && vx0) ? w10 : 0.f;
      wgt[q][3] = (vy1 && vx1) ? w11 : 0.f;
    }
  }

#pragma unroll
  for (int cc = 0; cc < 4; ++cc) {
    int c = c0 + cc;
    const float* s = sp + (size_t)c * HW;
    int kb = (csub * 4 + cc) * 9;
#pragma unroll
    for (int q = 0; q < 9; ++q) {
      float v;
      if (ZERO)
        v = wgt[q][0] * s[sid[q][0]];
      else
        v = wgt[q][0] * s[sid[q][0]] + wgt[q][1] * s[sid[q][1]] +
            wgt[q][2] * s[sid[q][2]] + wgt[q][3] * s[sid[q][3]];
      ushort_t hi, lo;
      split_bf(v, hi, lo);
      LH[nloc][kb + q] = hi;
      LL[nloc][kb + q] = lo;
    }
  }
  __syncthreads();

  const size_t rowbase = (size_t)b * HW + blockIdx.x * 64;
  const int kt0 = blockIdx.y * 144;
  for (int idx = t; idx < 64 * 18; idx += 256) {
    int r = idx / 18, ch = idx - (idx / 18) * 18;
    uint4 vh = *(const uint4*)&LH[r][ch * 8];
    uint4 vl = *(const uint4*)&LL[r][ch * 8];
    size_t g = (rowbase + r) * K + kt0 + ch * 8;
    *(uint4*)(dhi + g) = vh;
    *(uint4*)(dlo + g) = vl;
  }
}

// ---------------- general im2col (any Ksz<=5/stride/pad, zero-offset) ------
__global__ __launch_bounds__(256) void k_im2col_g(
    const float* __restrict__ src, ushort_t* __restrict__ dhi,
    ushort_t* __restrict__ dlo, int C, int Hin, int Win, int Hout, int Wout,
    int Ksz, int stride, int pad, int KP) {
  __shared__ ushort_t LH[64][100];
  __shared__ ushort_t LL[64][100];
  const int b = blockIdx.z;
  const int t = threadIdx.x;
  const int nloc = t >> 2, csub = t & 3;
  const int n0 = blockIdx.x * 64;
  const int n = n0 + nloc;
  const int c = blockIdx.y * 4 + csub;
  const int N = Hout * Wout;
  const int K2 = Ksz * Ksz;
  const int h = n / Wout, w = n - (n / Wout) * Wout;
  const bool val = (c < C) && (n < N);
  const float* s = src + ((size_t)b * C + c) * Hin * Win;
  for (int q = 0; q < K2; ++q) {
    int ki = q / Ksz, kj = q - (q / Ksz) * Ksz;
    int y = h * stride + ki - pad, x = w * stride + kj - pad;
    float v = 0.f;
    if (val && y >= 0 && y < Hin && x >= 0 && x < Win) v = s[y * Win + x];
    ushort_t hi, lo;
    split_bf(v, hi, lo);
    LH[nloc][csub * K2 + q] = hi;
    LL[nloc][csub * K2 + q] = lo;
  }
  __syncthreads();
  const int Nc = gridDim.x * 64;
  const int rl = 4 * K2;
  const int kt0 = blockIdx.y * rl;
  const int nu2 = rl >> 2;
  for (int idx = t; idx < 64 * nu2; idx += 256) {
    int r = idx / nu2, ch = idx - (idx / nu2) * nu2;
    uint2 vh = *(const uint2*)&LH[r][ch * 4];
    uint2 vl = *(const uint2*)&LL[r][ch * 4];
    size_t g = ((size_t)b * Nc + n0 + r) * KP + kt0 + ch * 4;
    *(uint2*)(dhi + g) = vh;
    *(uint2*)(dlo + g) = vl;
  }
}

__global__ void k_blend(const float* __restrict__ d0, const float* __restrict__ d1,
                        const float* __restrict__ sw0, const float* __restrict__ sw1,
                        float* __restrict__ out) {
  int idx = blockIdx.x * blockDim.x + threadIdx.x;
  const int tot = BN * 256 * HW;
  if (idx >= tot) return;
  int b = idx / (256 * HW);
  int n = idx % HW;
  float s0 = sw0[b * HW + n], s1 = sw1[b * HW + n];
  const float eps = 1e-8f;
  float na = fmaxf(fabsf(s0), eps), nb = fmaxf(fabsf(s1), eps);
  float Wx = (s0 * s1) / (na * nb);
  float Wy = (s1 * s1) / (nb * nb);
  float mx = fmaxf(Wx, Wy);
  float e0 = expf(Wx - mx), e1 = expf(Wy - mx);
  float inv = 1.f / (e0 + e1);
  out[idx] = d0[idx] * (e0 * inv) + d1[idx] * (e1 * inv);
}

// ---------------- split-bf16 MFMA GEMM, 128x128 tile, XCD n-swizzle --------
// grid.x = npad*mblocks flattened as f = n + m*npad (npad%8==0 => all m-blocks
// of one n-tile land on one XCD -> B fetched once). Always k-split + atomic.
__global__ __launch_bounds__(256) void k_mfma_nt2(
    const ushort_t* __restrict__ Ahi, const ushort_t* __restrict__ Alo,
    const ushort_t* __restrict__ Bhi, const ushort_t* __restrict__ Blo,
    float* __restrict__ Cmat, int M, int N, int K, int abatch, int kslices,
    int nblocks, int npad) {
  __shared__ ushort_t AsH[128][40];
  __shared__ ushort_t AsL[128][40];
  __shared__ ushort_t BsH[128][40];
  __shared__ ushort_t BsL[128][40];
  const int f = blockIdx.x;
  const int nb = f % npad;
  if (nb >= nblocks) return;
  const int mb = f / npad;
  const int zb = blockIdx.z;
  const int b = zb / kslices;
  const int slice = zb - b * kslices;
  const int nch = K >> 5;
  const int cper = (nch + kslices - 1) / kslices;
  const int kbeg = slice * cper * 32;
  const int kend = min(K, kbeg + cper * 32);
  const int n0 = nb * 128;
  const int m0 = mb * 128;
  const size_t aoff = abatch ? (size_t)b * M * K : (size_t)0;
  const ushort_t* AHp = Ahi + aoff;
  const ushort_t* ALp = Alo + aoff;
  const size_t boff = ((size_t)b * N + n0) * K;
  const ushort_t* BHp = Bhi + boff;
  const ushort_t* BLp = Blo + boff;
  const int t = threadIdx.x;
  const int lane = t & 63;
  const int wv = t >> 6;
  const int wm = wv >> 1, wn = wv & 1;
  const int l15 = lane & 15, quad = lane >> 4;

  const int arow = t >> 1;        // 0..127 (used for both A and B rows)
  const int acnk = (t & 1) * 2;   // chunk pair {0,1} or {2,3}

  f32x4 acc[4][4];
  const f32x4 z4 = {0.f, 0.f, 0.f, 0.f};
#pragma unroll
  for (int i = 0; i < 4; ++i)
#pragma unroll
    for (int j = 0; j < 4; ++j) acc[i][j] = z4;

  const bool aval = (m0 + arow) < M;
  const uint4 zero16 = {0u, 0u, 0u, 0u};

  for (int k0 = kbeg; k0 < kend; k0 += 32) {
    const size_t ao = (size_t)(m0 + arow) * K + k0;
    uint4 ah0 = aval ? *(const uint4*)(AHp + ao + acnk * 8) : zero16;
    uint4 ah1 = aval ? *(const uint4*)(AHp + ao + (acnk + 1) * 8) : zero16;
    uint4 al0 = aval ? *(const uint4*)(ALp + ao + acnk * 8) : zero16;
    uint4 al1 = aval ? *(const uint4*)(ALp + ao + (acnk + 1) * 8) : zero16;
    const size_t bo = (size_t)arow * K + k0;
    uint4 bh0 = *(const uint4*)(BHp + bo + acnk * 8);
    uint4 bh1 = *(const uint4*)(BHp + bo + (acnk + 1) * 8);
    uint4 bl0 = *(const uint4*)(BLp + bo + acnk * 8);
    uint4 bl1 = *(const uint4*)(BLp + bo + (acnk + 1) * 8);
    *(uint4*)&AsH[arow][acnk * 8] = ah0;
    *(uint4*)&AsH[arow][(acnk + 1) * 8] = ah1;
    *(uint4*)&AsL[arow][acnk * 8] = al0;
    *(uint4*)&AsL[arow][(acnk + 1) * 8] = al1;
    *(uint4*)&BsH[arow][acnk * 8] = bh0;
    *(uint4*)&BsH[arow][(acnk + 1) * 8] = bh1;
    *(uint4*)&BsL[arow][acnk * 8] = bl0;
    *(uint4*)&BsL[arow][(acnk + 1) * 8] = bl1;
    __syncthreads();

    bf16x8 afh[4], afl[4], bfh[4], bfl[4];
#pragma unroll
    for (int mt = 0; mt < 4; ++mt) {
      afh[mt] = *(const bf16x8*)&AsH[wm * 64 + mt * 16 + l15][quad * 8];
      afl[mt] = *(const bf16x8*)&AsL[wm * 64 + mt * 16 + l15][quad * 8];
    }
#pragma unroll
    for (int nt = 0; nt < 4; ++nt) {
      bfh[nt] = *(const bf16x8*)&BsH[wn * 64 + nt * 16 + l15][quad * 8];
      bfl[nt] = *(const bf16x8*)&BsL[wn * 64 + nt * 16 + l15][quad * 8];
    }
#pragma unroll
    for (int mt = 0; mt < 4; ++mt)
#pragma unroll
      for (int nt = 0; nt < 4; ++nt) {
        acc[mt][nt] = __builtin_amdgcn_mfma_f32_16x16x32_bf16(
            afh[mt], bfh[nt], acc[mt][nt], 0, 0, 0);
        acc[mt][nt] = __builtin_amdgcn_mfma_f32_16x16x32_bf16(
            afh[mt], bfl[nt], acc[mt][nt], 0, 0, 0);
        acc[mt][nt] = __builtin_amdgcn_mfma_f32_16x16x32_bf16(
            afl[mt], bfh[nt], acc[mt][nt], 0, 0, 0);
      }
    __syncthreads();
  }

  float* Cp = Cmat + (size_t)b * M * N;
#pragma unroll
  for (int mt = 0; mt < 4; ++mt) {
#pragma unroll
    for (int nt = 0; nt < 4; ++nt) {
#pragma unroll
      for (int reg = 0; reg < 4; ++reg) {
        int m = m0 + wm * 64 + mt * 16 + quad * 4 + reg;
        if (m >= M) continue;
        int n = n0 + wn * 64 + nt * 16 + l15;
        atomicAdd(&Cp[(size_t)m * N + n], acc[mt][nt][reg]);
      }
    }
  }
}

// ---------------- split-bf16 MFMA GEMM (128x64 tile, small-M fallback) -----
__global__ __launch_bounds__(256) void k_mfma_nt(
    const ushort_t* __restrict__ Ahi, const ushort_t* __restrict__ Alo,
    const ushort_t* __restrict__ Bhi, const ushort_t* __restrict__ Blo,
    float* __restrict__ Cmat, int M, int N, int K, int abatch, int relu,
    int kslices) {
  __shared__ ushort_t AsH[128][40];
  __shared__ ushort_t AsL[128][40];
  __shared__ ushort_t BsH[64][40];
  __shared__ ushort_t BsL[64][40];
  const int zb = blockIdx.z;
  const int b = zb / kslices;
  const int slice = zb - b * kslices;
  const int nch = K >> 5;
  const int cper = (nch + kslices - 1) / kslices;
  const int kbeg = slice * cper * 32;
  const int kend = min(K, kbeg + cper * 32);
  const int n0 = blockIdx.x * 64;
  const int m0 = blockIdx.y * 128;
  const size_t aoff = abatch ? (size_t)b * M * K : (size_t)0;
  const ushort_t* AHp = Ahi + aoff;
  const ushort_t* ALp = Alo + aoff;
  const size_t boff = ((size_t)b * N + n0) * K;
  const ushort_t* BHp = Bhi + boff;
  const ushort_t* BLp = Blo + boff;
  const int t = threadIdx.x;
  const int lane = t & 63;
  const int wv = t >> 6;
  const int wm = wv >> 1, wn = wv & 1;
  const int l15 = lane & 15, quad = lane >> 4;

  const int arow = t >> 1;
  const int acnk = (t & 1) * 2;
  const int brow = t >> 2;
  const int bcnk = t & 3;

  f32x4 acc[4][2];
  const f32x4 z4 = {0.f, 0.f, 0.f, 0.f};
#pragma unroll
  for (int i = 0; i < 4; ++i)
#pragma unroll
    for (int j = 0; j < 2; ++j) acc[i][j] = z4;

  const bool aval = (m0 + arow) < M;
  const uint4 zero16 = {0u, 0u, 0u, 0u};

  for (int k0 = kbeg; k0 < kend; k0 += 32) {
    const size_t arow_off = (size_t)(m0 + arow) * K + k0;
    uint4 ah0 = aval ? *(const uint4*)(AHp + arow_off + acnk * 8) : zero16;
    uint4 ah1 = aval ? *(const uint4*)(AHp + arow_off + (acnk + 1) * 8) : zero16;
    uint4 al0 = aval ? *(const uint4*)(ALp + arow_off + acnk * 8) : zero16;
    uint4 al1 = aval ? *(const uint4*)(ALp + arow_off + (acnk + 1) * 8) : zero16;
    const size_t brow_off = (size_t)brow * K + k0 + bcnk * 8;
    uint4 bh0 = *(const uint4*)(BHp + brow_off);
    uint4 bl0 = *(const uint4*)(BLp + brow_off);
    *(uint4*)&AsH[arow][acnk * 8] = ah0;
    *(uint4*)&AsH[arow][(acnk + 1) * 8] = ah1;
    *(uint4*)&AsL[arow][acnk * 8] = al0;
    *(uint4*)&AsL[arow][(acnk + 1) * 8] = al1;
    *(uint4*)&BsH[brow][bcnk * 8] = bh0;
    *(uint4*)&BsL[brow][bcnk * 8] = bl0;
    __syncthreads();

    bf16x8 afh[4], afl[4], bfh[2], bfl[2];
#pragma unroll
    for (int mt = 0; mt < 4; ++mt) {
      afh[mt] = *(const bf16x8*)&AsH[wm * 64 + mt * 16 + l15][quad * 8];
      afl[mt] = *(const bf16x8*)&AsL[wm * 64 + mt * 16 + l15][quad * 8];
    }
#pragma unroll
    for (int nt = 0; nt < 2; ++nt) {
      bfh[nt] = *(const bf16x8*)&BsH[wn * 32 + nt * 16 + l15][quad * 8];
      bfl[nt] = *(const bf16x8*)&BsL[wn * 32 + nt * 16 + l15][quad * 8];
    }
#pragma unroll
    for (int mt = 0; mt < 4; ++mt)
#pragma unroll
      for (int nt = 0; nt < 2; ++nt) {
        acc[mt][nt] = __builtin_amdgcn_mfma_f32_16x16x32_bf16(
            afh[mt], bfh[nt], acc[mt][nt], 0, 0, 0);
        acc[mt][nt] = __builtin_amdgcn_mfma_f32_16x16x32_bf16(
            afh[mt], bfl[nt], acc[mt][nt], 0, 0, 0);
        acc[mt][nt] = __builtin_amdgcn_mfma_f32_16x16x32_bf16(
            afl[mt], bfh[nt], acc[mt][nt], 0, 0, 0);
      }
    __syncthreads();
  }

  float* Cp = Cmat + (size_t)b * M * N;
#pragma unroll
  for (int mt = 0; mt < 4; ++mt) {
#pragma unroll
    for (int nt = 0; nt < 2; ++nt) {
#pragma unroll
      for (int reg = 0; reg < 4; ++reg) {
        int m = m0 + wm * 64 + mt * 16 + quad * 4 + reg;
        if (m >= M) continue;
        int n = n0 + wn * 32 + nt * 16 + l15;
        if (kslices > 1) {
          atomicAdd(&Cp[(size_t)m * N + n], acc[mt][nt][reg]);
        } else {
          float v = acc[mt][nt][reg];
          if (relu) v = fmaxf(v, 0.f);
          Cp[(size_t)m * N + n] = v;
        }
      }
    }
  }
}

// ---------------- off-conv MFMA: implicit zero-offset im2col (3x3 p1) ------
__global__ __launch_bounds__(256) void k_off_mfma(
    const ushort_t* __restrict__ Ahi, const ushort_t* __restrict__ Alo,
    const float* __restrict__ src, float* __restrict__ Cmat,
    int M, int C, int kslices) {
  const int N = HW;
  const int K = C * 9;
  __shared__ ushort_t BsH[64][40];
  __shared__ ushort_t BsL[64][40];
  __shared__ int spix[64][10];
  const int zb = blockIdx.z;
  const int b = zb / kslices;
  const int slice = zb - b * kslices;
  const int Kc = K / kslices;
  const int kbeg = slice * Kc;
  const int n0 = blockIdx.x * 64;
  const int t = threadIdx.x;
  const int lane = t & 63;
  const int wv = t >> 6;
  const int l15 = lane & 15, quad = lane >> 4;
  const float* sp = src + (size_t)b * C * HW;

  for (int i = t; i < 64 * 9; i += 256) {
    int r = i / 9, q = i - (i / 9) * 9;
    int n = n0 + r;
    int h = n / WWD, w = n - (n / WWD) * WWD;
    int ki = q / 3, kj = q - (q / 3) * 3;
    int y = h - 1 + ki, x = w - 1 + kj;
    spix[r][q] = (y >= 0 && y < HH && x >= 0 && x < WWD) ? (y * WWD + x) : -1;
  }
  __syncthreads();

  const int srow = t >> 2;
  const int scnk = t & 3;

  f32x4 acc[2];
  const f32x4 z4 = {0.f, 0.f, 0.f, 0.f};
  acc[0] = z4;
  acc[1] = z4;
  const uint4 zero16 = {0u, 0u, 0u, 0u};

  for (int k0 = kbeg; k0 < kbeg + Kc; k0 += 32) {
    {
      int k = k0 + scnk * 8;
      int c = k / 9;
      int q = k - c * 9;
#pragma unroll
      for (int j = 0; j < 8; ++j) {
        int ix = spix[srow][q];
        float v = (ix >= 0) ? sp[(size_t)c * HW + ix] : 0.f;
        ushort_t hi, lo;
        split_bf(v, hi, lo);
        BsH[srow][scnk * 8 + j] = hi;
        BsL[srow][scnk * 8 + j] = lo;
        ++q;
        if (q == 9) { q = 0; ++c; }
      }
    }
    __syncthreads();

    bf16x8 afh[2], afl[2], bfh, bfl;
#pragma unroll
    for (int mt = 0; mt < 2; ++mt) {
      int m = mt * 16 + l15;
      bool v = m < M;
      uint4 ah = v ? *(const uint4*)(Ahi + (size_t)m * K + k0 + quad * 8) : zero16;
      uint4 al = v ? *(const uint4*)(Alo + (size_t)m * K + k0 + quad * 8) : zero16;
      afh[mt] = *(const bf16x8*)&ah;
      afl[mt] = *(const bf16x8*)&al;
    }
    bfh = *(const bf16x8*)&BsH[wv * 16 + l15][quad * 8];
    bfl = *(const bf16x8*)&BsL[wv * 16 + l15][quad * 8];
#pragma unroll
    for (int mt = 0; mt < 2; ++mt) {
      acc[mt] = __builtin_amdgcn_mfma_f32_16x16x32_bf16(afh[mt], bfh, acc[mt], 0, 0, 0);
      acc[mt] = __builtin_amdgcn_mfma_f32_16x16x32_bf16(afh[mt], bfl, acc[mt], 0, 0, 0);
      acc[mt] = __builtin_amdgcn_mfma_f32_16x16x32_bf16(afl[mt], bfh, acc[mt], 0, 0, 0);
    }
    __syncthreads();
  }

  float* Cp = Cmat + (size_t)b * M * N;
#pragma unroll
  for (int mt = 0; mt < 2; ++mt)
#pragma unroll
    for (int reg = 0; reg < 4; ++reg) {
      int m = mt * 16 + quad * 4 + reg;
      if (m >= M) continue;
      int n = n0 + wv * 16 + l15;
      atomicAdd(&Cp[(size_t)m * N + n], acc[mt][reg]);
    }
}

// ---------------- split-bf16 M32-tile GEMM over cols -----------------------
__global__ __launch_bounds__(256) void k_gemm_sk(
    const ushort_t* __restrict__ Ahi, const ushort_t* __restrict__ Alo,
    const ushort_t* __restrict__ Bhi, const ushort_t* __restrict__ Blo,
    const float* __restrict__ bias, float* __restrict__ Cmat,
    int M, int N, int Nc, int KP, int kslices, int relu) {
  __shared__ ushort_t BsH[64][40];
  __shared__ ushort_t BsL[64][40];
  const int zb = blockIdx.z;
  const int b = zb / kslices;
  const int slice = zb - b * kslices;
  const int nch = KP >> 5;
  const int cper = (nch + kslices - 1) / kslices;
  const int kbeg = slice * cper * 32;
  const int kend = min(KP, kbeg + cper * 32);
  const int n0 = blockIdx.x * 64;
  const int m0 = blockIdx.y * 32;
  const int t = threadIdx.x;
  const int lane = t & 63;
  const int wv = t >> 6;
  const int l15 = lane & 15, quad = lane >> 4;
  const ushort_t* BHp = Bhi + ((size_t)b * Nc + n0) * KP;
  const ushort_t* BLp = Blo + ((size_t)b * Nc + n0) * KP;
  const int srow = t >> 2, scnk = t & 3;

  f32x4 acc[2];
  const f32x4 z4 = {0.f, 0.f, 0.f, 0.f};
  acc[0] = z4;
  acc[1] = z4;
  const uint4 zero16 = {0u, 0u, 0u, 0u};

  for (int k0 = kbeg; k0 < kend; k0 += 32) {
    const size_t bo = (size_t)srow * KP + k0 + scnk * 8;
    uint4 bh = *(const uint4*)(BHp + bo);
    uint4 bl = *(const uint4*)(BLp + bo);
    *(uint4*)&BsH[srow][scnk * 8] = bh;
    *(uint4*)&BsL[srow][scnk * 8] = bl;
    __syncthreads();

    bf16x8 afh[2], afl[2], bfh, bfl;
#pragma unroll
    for (int mt = 0; mt < 2; ++mt) {
      int m = m0 + mt * 16 + l15;
      bool v = m < M;
      uint4 ah = v ? *(const uint4*)(Ahi + (size_t)m * KP + k0 + quad * 8) : zero16;
      uint4 al = v ? *(const uint4*)(Alo + (size_t)m * KP + k0 + quad * 8) : zero16;
      afh[mt] = *(const bf16x8*)&ah;
      afl[mt] = *(const bf16x8*)&al;
    }
    bfh = *(const bf16x8*)&BsH[wv * 16 + l15][quad * 8];
    bfl = *(const bf16x8*)&BsL[wv * 16 + l15][quad * 8];
#pragma unroll
    for (int mt = 0; mt < 2; ++mt) {
      acc[mt] = __builtin_amdgcn_mfma_f32_16x16x32_bf16(afh[mt], bfh, acc[mt], 0, 0, 0);
      acc[mt] = __builtin_amdgcn_mfma_f32_16x16x32_bf16(afh[mt], bfl, acc[mt], 0, 0, 0);
      acc[mt] = __builtin_amdgcn_mfma_f32_16x16x32_bf16(afl[mt], bfh, acc[mt], 0, 0, 0);
    }
    __syncthreads();
  }

  float* Cp = Cmat + (size_t)b * M * N;
  const int n = n0 + wv * 16 + l15;
  if (n < N) {
#pragma unroll
    for (int mt = 0; mt < 2; ++mt)
#pragma unroll
      for (int reg = 0; reg < 4; ++reg) {
        int m = m0 + mt * 16 + quad * 4 + reg;
        if (m >= M) continue;
        if (kslices > 1) {
          atomicAdd(&Cp[(size_t)m * N + n], acc[mt][reg]);
        } else {
          float v = acc[mt][reg];
          if (bias != nullptr) v += bias[m];
          if (relu) v = fmaxf(v, 0.f);
          Cp[(size_t)m * N + n] = v;
        }
      }
  }
}

// ---------------------------------------------------------------------------

extern "C" void kernel_launch(void* const* d_in, const int* in_sizes, int n_in,
                              void* d_out, int out_size, void* d_ws, size_t ws_size,
                              hipStream_t stream) {
  (void)in_sizes; (void)n_in; (void)out_size;

  const float* R0     = (const float*)d_in[0];
  const float* T0     = (const float*)d_in[1];
  const float* inp    = (const float*)d_in[2];
  const float* enc0_w = (const float*)d_in[3];
  const float* enc0_b = (const float*)d_in[4];
  const float* enc1_w = (const float*)d_in[5];
  const float* enc1_b = (const float*)d_in[6];
  const float* off_w[4] = {(const float*)d_in[7], (const float*)d_in[8],
                           (const float*)d_in[9], (const float*)d_in[10]};
  const float* def_w[3] = {(const float*)d_in[11], (const float*)d_in[12],
                           (const float*)d_in[13]};
  const float* w0a = (const float*)d_in[14];
  const float* w0b = (const float*)d_in[15];
  const float* w0c = (const float*)d_in[16];
  const float* w1a = (const float*)d_in[17];
  const float* w1b = (const float*)d_in[18];
  const float* w1c = (const float*)d_in[19];
  const float* wx_w  = (const float*)d_in[20];
  const float* wx_b  = (const float*)d_in[21];
  const float* wxf_w = (const float*)d_in[22];
  const float* wxf_b = (const float*)d_in[23];
  const float* s1w = (const float*)d_in[24];
  const float* s2w = (const float*)d_in[25];
  const float* s3w = (const float*)d_in[26];

  float* ws = (float*)d_ws;
  size_t used = 0;
  auto alloc = [&](size_t n) { float* p = ws + used; used += n; return p; };
  float* xf      = alloc(1179648);
  float* yf      = alloc(1179648);
  float* xenc    = alloc(294912);
  float* yenc    = alloc(294912);
  float* featA   = alloc(2359296);
  float* featB   = alloc(2359296);
  float* offb    = alloc(82944);
  float* offset0 = alloc(82944);
  float* offset1 = alloc(82944);
  float* featw   = alloc(815616);
  float* featw2  = alloc(815616);
  float* wb1     = alloc(73728);
  float* wb2     = alloc(18432);
  float* wb3     = alloc(18432);
  float* fw1     = alloc(512);
  float* fw2     = alloc(512);
  float* deform0 = alloc(1179648);
  float* deform1 = alloc(1179648);
  float* sn1     = alloc(589824);
  float* sn2     = alloc(294912);
  float* sw0     = alloc(4608);
  float* sw1     = alloc(4608);
  ushort_t *defw_h[3], *defw_l[3];
  for (int i = 0; i < 3; ++i) {
    defw_h[i] = (ushort_t*)alloc(1179648);
    defw_l[i] = (ushort_t*)alloc(1179648);
  }
  ushort_t *offw_h[4], *offw_l[4];
  for (int i = 0; i < 4; ++i) {
    offw_h[i] = (ushort_t*)alloc(41472);
    offw_l[i] = (ushort_t*)alloc(41472);
  }
  ushort_t* wxf_h = (ushort_t*)alloc(589824);
  ushort_t* wxf_l = (ushort_t*)alloc(589824);
  ushort_t* s1w_h = (ushort_t*)alloc(147456);
  ushort_t* s1w_l = (ushort_t*)alloc(147456);
  ushort_t* s2w_h = (ushort_t*)alloc(36864);
  ushort_t* s2w_l = (ushort_t*)alloc(36864);
  ushort_t* w0a_h = (ushort_t*)alloc(144384);
  ushort_t* w0a_l = (ushort_t*)alloc(144384);
  ushort_t* w1a_h = (ushort_t*)alloc(144384);
  ushort_t* w1a_l = (ushort_t*)alloc(144384);
  ushort_t* w0b_h = (ushort_t*)alloc(51200);
  ushort_t* w0b_l = (ushort_t*)alloc(51200);
  ushort_t* w1b_h = (ushort_t*)alloc(51200);
  ushort_t* w1b_l = (ushort_t*)alloc(51200);
  ushort_t* w0c_h = (ushort_t*)alloc(50976);
  ushort_t* w0c_l = (ushort_t*)alloc(50976);
  ushort_t* w1c_h = (ushort_t*)alloc(73728);
  ushort_t* w1c_l = (ushort_t*)alloc(73728);
  ushort_t* e0w_h = (ushort_t*)alloc(8192);
  ushort_t* e0w_l = (ushort_t*)alloc(8192);
  ushort_t* e1w_h = (ushort_t*)alloc(8192);
  ushort_t* e1w_l = (ushort_t*)alloc(8192);
  ushort_t* s3w_h = (ushort_t*)alloc(288);
  ushort_t* s3w_l = (ushort_t*)alloc(288);
  ushort_t* wxad_h = (ushort_t*)alloc(288864);
  ushort_t* wxad_l = (ushort_t*)alloc(288864);
  ushort_t* cols_h = (ushort_t*)alloc(10616832);
  ushort_t* cols_l = (ushort_t*)alloc(10616832);
  if (used * sizeof(float) > ws_size) return;

  // 128x128-tile GEMM with XCD n-swizzle (N=2304 -> 18 n-blocks, npad=24)
  auto mfma2 = [&](const ushort_t* Ah, const ushort_t* Al, float* Cmat, int M,
                   int K, int abatch, int ks) {
    hipMemsetAsync(Cmat, 0, (size_t)BN * M * 2304 * sizeof(float), stream);
    int mb = (M + 127) / 128;
    dim3 grid(24 * mb, 1, BN * ks);
    k_mfma_nt2<<<grid, 256, 0, stream>>>(Ah, Al, cols_h, cols_l, Cmat, M, 2304,
                                         K, abatch, ks, 18, 24);
  };
  auto mfma = [&](const ushort_t* Ah, const ushort_t* Al, float* Cmat, int M,
                  int K, int abatch, int relu, int ks) {
    if (ks > 1)
      hipMemsetAsync(Cmat, 0, (size_t)BN * M * 2304 * sizeof(float), stream);
    dim3 grid(2304 / 64, (M + 127) / 128, BN * ks);
    k_mfma_nt<<<grid, 256, 0, stream>>>(Ah, Al, cols_h, cols_l, Cmat, M, 2304, K,
                                        abatch, relu, ks);
  };
  auto off_conv = [&](const ushort_t* Ah, const ushort_t* Al, const float* src,
                      float* Cmat, int C) {
    hipMemsetAsync(Cmat, 0, (size_t)BN * 18 * HW * sizeof(float), stream);
    dim3 grid(36, 1, BN * 8);
    k_off_mfma<<<grid, 256, 0, stream>>>(Ah, Al, src, Cmat, 18, C, 8);
  };
  auto im2col = [&](const float* src, const float* off, int C) {
    dim3 grid(36, C * 9 / 144, BN);
    if (off == nullptr)
      k_im2col2<1><<<grid, 256, 0, stream>>>(src, nullptr, cols_h, cols_l, C);
    else
      k_im2col2<0><<<grid, 256, 0, stream>>>(src, off, cols_h, cols_l, C);
  };
  auto im2col_g = [&](const float* src, int C, int Hin, int Win, int Hout,
                      int Wout, int Ksz, int stridec, int pad, int KP) {
    dim3 grid((Hout * Wout + 63) / 64, (C + 3) / 4, BN);
    k_im2col_g<<<grid, 256, 0, stream>>>(src, cols_h, cols_l, C, Hin, Win, Hout,
                                         Wout, Ksz, stridec, pad, KP);
  };
  auto gemm_sk = [&](const ushort_t* Ah, const ushort_t* Al, const float* bias,
                     float* Cmat, int M, int N, int KP, int kslices, int relu) {
    int Nc = ((N + 63) / 64) * 64;
    if (kslices > 1)
      hipMemsetAsync(Cmat, 0, (size_t)BN * M * N * sizeof(float), stream);
    dim3 grid(Nc / 64, (M + 31) / 32, BN * kslices);
    k_gemm_sk<<<grid, 256, 0, stream>>>(Ah, Al, cols_h, cols_l, bias, Cmat, M,
                                        N, Nc, KP, kslices, relu);
  };

  // ---- weight conversions ----
  for (int i = 0; i < 3; ++i)
    k_w2b<<<(2359296 + 255) / 256, 256, 0, stream>>>(def_w[i], defw_h[i],
                                                     defw_l[i], 2359296);
  for (int i = 0; i < 4; ++i)
    k_w2b<<<(82944 + 255) / 256, 256, 0, stream>>>(off_w[i], offw_h[i],
                                                   offw_l[i], 82944);
  k_w2b<<<(294912 + 255) / 256, 256, 0, stream>>>(s1w, s1w_h, s1w_l, 294912);
  k_w2b<<<(73728 + 255) / 256, 256, 0, stream>>>(s2w, s2w_h, s2w_l, 73728);
  k_w2b_pad<<<(64 * 4512 + 255) / 256, 256, 0, stream>>>(w0a, w0a_h, w0a_l, 64, 4425, 4512);
  k_w2b_pad<<<(64 * 4512 + 255) / 256, 256, 0, stream>>>(w1a, w1a_h, w1a_l, 64, 4425, 4512);
  k_w2b_pad<<<(64 * 1600 + 255) / 256, 256, 0, stream>>>(w0b, w0b_h, w0b_l, 64, 1600, 1600);
  k_w2b_pad<<<(64 * 1600 + 255) / 256, 256, 0, stream>>>(w1b, w1b_h, w1b_l, 64, 1600, 1600);
  k_w2b_pad<<<(177 * 576 + 255) / 256, 256, 0, stream>>>(w0c, w0c_h, w0c_l, 177, 576, 576);
  k_w2b_pad<<<(256 * 576 + 255) / 256, 256, 0, stream>>>(w1c, w1c_h, w1c_l, 256, 576, 576);
  k_w2b_pad<<<(64 * 256 + 255) / 256, 256, 0, stream>>>(enc0_w, e0w_h, e0w_l, 64, 256, 256);
  k_w2b_pad<<<(64 * 256 + 255) / 256, 256, 0, stream>>>(enc1_w, e1w_h, e1w_l, 64, 256, 256);
  k_w2b_pad<<<(576 + 255) / 256, 256, 0, stream>>>(s3w, s3w_h, s3w_l, 1, 576, 576);

  // ---- split + encoders ----
  k_split_xy<<<4608, 256, 0, stream>>>(inp, xf, yf);
  im2col_g(xf, 256, 48, 48, 48, 48, 1, 1, 0, 256);
  gemm_sk(e0w_h, e0w_l, enc0_b, xenc, 64, 2304, 256, 1, 0);
  im2col_g(yf, 256, 48, 48, 48, 48, 1, 1, 0, 256);
  gemm_sk(e1w_h, e1w_l, enc1_b, yenc, 64, 2304, 256, 1, 0);

  // ---- stsn_offset passes ----
  auto stsn = [&](const float* srcA, const float* srcB, float* offset_out) {
    k_concat512<<<(BN * 512 * HW) / 256, 256, 0, stream>>>(srcA, srcB, featA);
    float* cur = featA;
    float* nxt = featB;
    for (int i = 0; i < 3; ++i) {
      off_conv(offw_h[i], offw_l[i], cur, offb, 512);
      im2col(cur, offb, 512);
      mfma2(defw_h[i], defw_l[i], nxt, 512, 4608, 0, 8);
      float* tmp = cur; cur = nxt; nxt = tmp;
    }
    off_conv(offw_h[3], offw_l[3], cur, offset_out, 512);
  };
  stsn(xf, yf, offset0);
  stsn(yf, yf, offset1);

  // ---- astsn_weight + adaptive deform conv ----
  auto branch = [&](const float* fin, const ushort_t* wah, const ushort_t* wal,
                    const ushort_t* wbh, const ushort_t* wbl,
                    const ushort_t* wch, const ushort_t* wcl, int Mout,
                    float* fwout) {
    im2col_g(fin, 177, 48, 48, 24, 24, 5, 2, 2, 4512);
    gemm_sk(wah, wal, nullptr, wb1, 64, 576, 4512, 8, 0);
    k_relu<<<(BN * 64 * 576 + 255) / 256, 256, 0, stream>>>(wb1, BN * 64 * 576);
    im2col_g(wb1, 64, 24, 24, 12, 12, 5, 2, 2, 1600);
    gemm_sk(wbh, wbl, nullptr, wb2, 64, 144, 1600, 4, 0);
    k_relu<<<(BN * 64 * 144 + 255) / 256, 256, 0, stream>>>(wb2, BN * 64 * 144);
    im2col_g(wb2, 64, 12, 12, 6, 6, 3, 2, 1, 576);
    gemm_sk(wch, wcl, nullptr, wb3, Mout, 36, 576, 2, 0);
    k_mean<<<(BN * Mout + 255) / 256, 256, 0, stream>>>(wb3, fwout, Mout, 36);
  };

  for (int p = 0; p < 2; ++p) {
    k_correlation<<<882, 256, 0, stream>>>(R0, T0, p, featw);
    k_pack_enc<<<1152, 256, 0, stream>>>(p ? yenc : xenc, yenc, featw);
    branch(featw, w0a_h, w0a_l, w0b_h, w0b_l, w0c_h, w0c_l, 177, fw1);
    k_w2b_fw_pad<<<(BN * 177 * 1632 + 255) / 256, 256, 0, stream>>>(
        wx_w, wx_b, fw1, wxad_h, wxad_l, 177, 1593, 1632);
    im2col_g(featw, 177, 48, 48, 48, 48, 3, 1, 1, 1632);
    mfma2(wxad_h, wxad_l, featw2, 177, 1632, 1, 2);
    k_relu<<<(BN * 177 * HW + 255) / 256, 256, 0, stream>>>(featw2, BN * 177 * HW);
    branch(featw2, w1a_h, w1a_l, w1b_h, w1b_l, w1c_h, w1c_l, 256, fw2);
    k_w2b_fw<<<(BN * 256 * 2304 + 255) / 256, 256, 0, stream>>>(
        wxf_w, wxf_b, fw2, wxf_h, wxf_l, 256, 2304);
    im2col(p ? yf : xf, p ? offset1 : offset0, 256);
    mfma2(wxf_h, wxf_l, p ? deform1 : deform0, 256, 2304, 1, 4);
  }

  // ---- s_net x2 ----
  for (int p = 0; p < 2; ++p) {
    const float* din = p ? deform1 : deform0;
    float* swp = p ? sw1 : sw0;
    im2col(din, nullptr, 256);
    mfma2(s1w_h, s1w_l, sn1, 128, 2304, 0, 4);
    k_relu<<<(BN * 128 * HW + 255) / 256, 256, 0, stream>>>(sn1, BN * 128 * HW);
    im2col(sn1, nullptr, 128);
    mfma(s2w_h, s2w_l, sn2, 64, 1152, 0, 0, 4);
    k_relu<<<(BN * 64 * HW + 255) / 256, 256, 0, stream>>>(sn2, BN * 64 * HW);
    im2col_g(sn2, 64, 48, 48, 48, 48, 3, 1, 1, 576);
    gemm_sk(s3w_h, s3w_l, nullptr, swp, 1, 2304, 576, 1, 1);
  }

  // ---- blend ----
  k_blend<<<4608, 256, 0, stream>>>(deform0, deform1, sw0, sw1, (float*)d_out);
}

// Round 12
// 2426.742 us; speedup vs baseline: 1.1337x; 1.1337x over previous
//
#include <hip/hip_runtime.h>
#include <stdint.h>

// ---------------------------------------------------------------------------
// Round 12: revert big GEMM to r10-proven k_mfma_nt (128x64, ks-split); batch
// the two independent astsn/adaptive-deform/s_net passes as batch-4 (xy4 /
// enc4 contiguous slot tricks) -> ~30 fewer dispatches, 2x occupancy on all
// small kernels. stsn stays batch-2 (cols memory).
// ---------------------------------------------------------------------------

typedef unsigned short ushort_t;
typedef __attribute__((ext_vector_type(8))) short bf16x8;
typedef __attribute__((ext_vector_type(4))) float f32x4;

#define BN 2
#define HH 48
#define WWD 48
#define HW 2304

__device__ __forceinline__ float b2f(ushort_t h) {
  union { uint32_t u; float f; } v; v.u = ((uint32_t)h) << 16; return v.f;
}
__device__ __forceinline__ ushort_t f2b(float f) {
  union { float f; uint32_t u; } v; v.f = f;
  uint32_t u = v.u;
  uint32_t r = (u + 0x7fffu + ((u >> 16) & 1u)) >> 16;
  return (ushort_t)r;
}
__device__ __forceinline__ void split_bf(float v, ushort_t& hi, ushort_t& lo) {
  hi = f2b(v);
  lo = f2b(v - b2f(hi));
}

// ---------------- elementwise / packing kernels ----------------------------

__global__ void k_split_xy(const float* __restrict__ in, float* __restrict__ xf,
                           float* __restrict__ yf) {
  int idx = blockIdx.x * blockDim.x + threadIdx.x;
  const int tot = BN * 256 * HW;
  if (idx >= tot) return;
  int b = idx / (256 * HW);
  int r = idx - b * (256 * HW);
  xf[idx] = in[(size_t)(2 * b) * (256 * HW) + r];
  yf[idx] = in[(size_t)(2 * b + 1) * (256 * HW) + r];
}

__global__ void k_concat512(const float* __restrict__ a, const float* __restrict__ c2,
                            float* __restrict__ feat) {
  int idx = blockIdx.x * blockDim.x + threadIdx.x;
  const int tot = BN * 512 * HW;
  if (idx >= tot) return;
  int b = idx / (512 * HW);
  int r = idx - b * (512 * HW);
  int c = r / HW;
  int n = r - c * HW;
  feat[idx] = (c < 256) ? a[(b * 256 + c) * HW + n]
                        : c2[(b * 256 + (c - 256)) * HW + n];
}

__global__ void k_relu(float* __restrict__ p, int n) {
  int idx = blockIdx.x * blockDim.x + threadIdx.x;
  if (idx < n) p[idx] = fmaxf(p[idx], 0.f);
}

__global__ void k_mean(const float* __restrict__ src, float* __restrict__ dst,
                       int Mtot, int N) {
  int idx = blockIdx.x * blockDim.x + threadIdx.x;
  if (idx >= Mtot) return;
  const float* p = src + (size_t)idx * N;
  float s = 0.f;
  for (int i = 0; i < N; ++i) s += p[i];
  dst[idx] = s / (float)N;
}

__global__ void k_w2b(const float* __restrict__ w, ushort_t* __restrict__ ohi,
                      ushort_t* __restrict__ olo, int n) {
  int idx = blockIdx.x * blockDim.x + threadIdx.x;
  if (idx < n) split_bf(w[idx], ohi[idx], olo[idx]);
}

__global__ void k_w2b_pad(const float* __restrict__ w, ushort_t* __restrict__ ohi,
                          ushort_t* __restrict__ olo, int M, int K, int Kpad) {
  int idx = blockIdx.x * blockDim.x + threadIdx.x;
  if (idx >= M * Kpad) return;
  int m = idx / Kpad, k = idx - m * Kpad;
  float v = (k < K) ? w[(size_t)m * K + k] : 0.f;
  split_bf(v, ohi[idx], olo[idx]);
}

// per-batch adaptive weight (NB batches)
__global__ void k_w2b_fw(const float* __restrict__ w, const float* __restrict__ wb,
                         const float* __restrict__ fw, ushort_t* __restrict__ ohi,
                         ushort_t* __restrict__ olo, int M, int K, int NB) {
  int idx = blockIdx.x * blockDim.x + threadIdx.x;
  int tot = NB * M * K;
  if (idx >= tot) return;
  int b = idx / (M * K);
  int r = idx - b * (M * K);
  int m = r / K;
  split_bf(fw[b * M + m] * w[r] + wb[r], ohi[idx], olo[idx]);
}

__global__ void k_w2b_fw_pad(const float* __restrict__ w, const float* __restrict__ wb,
                             const float* __restrict__ fw, ushort_t* __restrict__ ohi,
                             ushort_t* __restrict__ olo, int M, int K, int Kpad,
                             int NB) {
  int idx = blockIdx.x * blockDim.x + threadIdx.x;
  int tot = NB * M * Kpad;
  if (idx >= tot) return;
  int b = idx / (M * Kpad);
  int r = idx - b * (M * Kpad);
  int m = r / Kpad;
  int k = r - m * Kpad;
  float v = 0.f;
  if (k < K) v = fw[b * M + m] * w[(size_t)m * K + k] + wb[(size_t)m * K + k];
  split_bf(v, ohi[idx], olo[idx]);
}

// batch-4 correlation: bb = pass*2+b; a = R0[b*2+pass], bsrc = T0[b*2+1]
__global__ void k_correlation4(const float* __restrict__ R0,
                               const float* __restrict__ T0,
                               float* __restrict__ featw) {
  int idx = blockIdx.x * blockDim.x + threadIdx.x;
  const int tot = 4 * 49 * HW;
  if (idx >= tot) return;
  int n = idx % HW;
  int t = idx / HW;
  int d = t % 49;
  int bb = t / 49;
  int pass = bb >> 1, b = bb & 1;
  int dyi = d / 7, dxi = d - dyi * 7;
  int dy = 2 * (dyi - 3), dx = 2 * (dxi - 3);
  int h = n / WWD, w = n - h * WWD;
  int hb = h + dy, wb = w + dx;
  float s = 0.f;
  if (hb >= 0 && hb < HH && wb >= 0 && wb < WWD) {
    const float* ap = R0 + ((size_t)(b * 2 + pass) * 64) * HW + n;
    const float* bp = T0 + ((size_t)(b * 2 + 1) * 64) * HW + hb * WWD + wb;
#pragma unroll 8
    for (int c = 0; c < 64; ++c) s += ap[(size_t)c * HW] * bp[(size_t)c * HW];
  }
  featw[((size_t)bb * 177 + d) * HW + n] = s * (1.f / 64.f);
}

// batch-4 enc pack: enc4 = [xe0,xe1,ye0,ye1]; ch49 = enc4[bb], ch113 = ye[b]
__global__ void k_pack_enc4(const float* __restrict__ enc4,
                            float* __restrict__ featw) {
  int idx = blockIdx.x * blockDim.x + threadIdx.x;
  const int tot = 4 * 64 * HW;
  if (idx >= tot) return;
  int bb = idx / (64 * HW);
  int r = idx - bb * (64 * HW);
  featw[((size_t)bb * 177 + 49) * HW + r] = enc4[(size_t)bb * 64 * HW + r];
  featw[((size_t)bb * 177 + 113) * HW + r] =
      enc4[(size_t)(2 + (bb & 1)) * 64 * HW + r];
}

// ---------------- im2col v2 (3x3 pad1 on 48x48, deform/zero) ---------------
template <int ZERO>
__global__ __launch_bounds__(256) void k_im2col2(
    const float* __restrict__ src, const float* __restrict__ off,
    ushort_t* __restrict__ dhi, ushort_t* __restrict__ dlo, int C) {
  __shared__ ushort_t LH[64][152];
  __shared__ ushort_t LL[64][152];
  const int b = blockIdx.z;
  const int t = threadIdx.x;
  const int nloc = t >> 2;
  const int csub = t & 3;
  const int n = blockIdx.x * 64 + nloc;
  const int c0 = blockIdx.y * 16 + csub * 4;
  const int K = C * 9;
  const int h = n / WWD, w = n - (n / WWD) * WWD;
  const float* sp = src + (size_t)b * C * HW;

  float wgt[9][4];
  int sid[9][4];
  if (ZERO) {
#pragma unroll
    for (int q = 0; q < 9; ++q) {
      int ki = q / 3, kj = q - (q / 3) * 3;
      int y = h - 1 + ki, x = w - 1 + kj;
      bool v = (y >= 0 && y < HH && x >= 0 && x < WWD);
      sid[q][0] = v ? y * WWD + x : 0;
      wgt[q][0] = v ? 1.f : 0.f;
    }
  } else {
#pragma unroll
    for (int q = 0; q < 9; ++q) {
      int ki = q / 3, kj = q - (q / 3) * 3;
      float dy = off[((size_t)(b * 9 + q) * 2 + 0) * HW + n];
      float dx = off[((size_t)(b * 9 + q) * 2 + 1) * HW + n];
      float py = (float)(h - 1 + ki) + dy;
      float px = (float)(w - 1 + kj) + dx;
      float fy = floorf(py), fx = floorf(px);
      float ay = py - fy, ax = px - fx;
      int y0 = (int)fy, x0 = (int)fx;
      int y1 = y0 + 1, x1 = x0 + 1;
      float w00 = (1.f - ay) * (1.f - ax), w01 = (1.f - ay) * ax;
      float w10 = ay * (1.f - ax), w11 = ay * ax;
      bool vy0 = (y0 >= 0 && y0 < HH), vy1 = (y1 >= 0 && y1 < HH);
      bool vx0 = (x0 >= 0 && x0 < WWD), vx1 = (x1 >= 0 && x1 < WWD);
      int cy0 = min(max(y0, 0), HH - 1), cy1 = min(max(y1, 0), HH - 1);
      int cx0 = min(max(x0, 0), WWD - 1), cx1 = min(max(x1, 0), WWD - 1);
      sid[q][0] = cy0 * WWD + cx0;
      sid[q][1] = cy0 * WWD + cx1;
      sid[q][2] = cy1 * WWD + cx0;
      sid[q][3] = cy1 * WWD + cx1;
      wgt[q][0] = (vy0 && vx0) ? w00 : 0.f;
      wgt[q][1] = (vy0 && vx1) ? w01 : 0.f;
      wgt[q][2] = (vy1 && vx0) ? w10 : 0.f;
      wgt[q][3] = (vy1 && vx1) ? w11 : 0.f;
    }
  }

#pragma unroll
  for (int cc = 0; cc < 4; ++cc) {
    int c = c0 + cc;
    const float* s = sp + (size_t)c * HW;
    int kb = (csub * 4 + cc) * 9;
#pragma unroll
    for (int q = 0; q < 9; ++q) {
      float v;
      if (ZERO)
        v = wgt[q][0] * s[sid[q][0]];
      else
        v = wgt[q][0] * s[sid[q][0]] + wgt[q][1] * s[sid[q][1]] +
            wgt[q][2] * s[sid[q][2]] + wgt[q][3] * s[sid[q][3]];
      ushort_t hi, lo;
      split_bf(v, hi, lo);
      LH[nloc][kb + q] = hi;
      LL[nloc][kb + q] = lo;
    }
  }
  __syncthreads();

  const size_t rowbase = (size_t)b * HW + blockIdx.x * 64;
  const int kt0 = blockIdx.y * 144;
  for (int idx = t; idx < 64 * 18; idx += 256) {
    int r = idx / 18, ch = idx - (idx / 18) * 18;
    uint4 vh = *(const uint4*)&LH[r][ch * 8];
    uint4 vl = *(const uint4*)&LL[r][ch * 8];
    size_t g = (rowbase + r) * K + kt0 + ch * 8;
    *(uint4*)(dhi + g) = vh;
    *(uint4*)(dlo + g) = vl;
  }
}

// ---------------- general im2col (any Ksz<=5/stride/pad, zero-offset) ------
__global__ __launch_bounds__(256) void k_im2col_g(
    const float* __restrict__ src, ushort_t* __restrict__ dhi,
    ushort_t* __restrict__ dlo, int C, int Hin, int Win, int Hout, int Wout,
    int Ksz, int stride, int pad, int KP) {
  __shared__ ushort_t LH[64][100];
  __shared__ ushort_t LL[64][100];
  const int b = blockIdx.z;
  const int t = threadIdx.x;
  const int nloc = t >> 2, csub = t & 3;
  const int n0 = blockIdx.x * 64;
  const int n = n0 + nloc;
  const int c = blockIdx.y * 4 + csub;
  const int N = Hout * Wout;
  const int K2 = Ksz * Ksz;
  const int h = n / Wout, w = n - (n / Wout) * Wout;
  const bool val = (c < C) && (n < N);
  const float* s = src + ((size_t)b * C + c) * Hin * Win;
  for (int q = 0; q < K2; ++q) {
    int ki = q / Ksz, kj = q - (q / Ksz) * Ksz;
    int y = h * stride + ki - pad, x = w * stride + kj - pad;
    float v = 0.f;
    if (val && y >= 0 && y < Hin && x >= 0 && x < Win) v = s[y * Win + x];
    ushort_t hi, lo;
    split_bf(v, hi, lo);
    LH[nloc][csub * K2 + q] = hi;
    LL[nloc][csub * K2 + q] = lo;
  }
  __syncthreads();
  const int Nc = gridDim.x * 64;
  const int rl = 4 * K2;
  const int kt0 = blockIdx.y * rl;
  const int nu2 = rl >> 2;
  for (int idx = t; idx < 64 * nu2; idx += 256) {
    int r = idx / nu2, ch = idx - (idx / nu2) * nu2;
    uint2 vh = *(const uint2*)&LH[r][ch * 4];
    uint2 vl = *(const uint2*)&LL[r][ch * 4];
    size_t g = ((size_t)b * Nc + n0 + r) * KP + kt0 + ch * 4;
    *(uint2*)(dhi + g) = vh;
    *(uint2*)(dlo + g) = vl;
  }
}

__global__ void k_blend(const float* __restrict__ d0, const float* __restrict__ d1,
                        const float* __restrict__ sw0, const float* __restrict__ sw1,
                        float* __restrict__ out) {
  int idx = blockIdx.x * blockDim.x + threadIdx.x;
  const int tot = BN * 256 * HW;
  if (idx >= tot) return;
  int b = idx / (256 * HW);
  int n = idx % HW;
  float s0 = sw0[b * HW + n], s1 = sw1[b * HW + n];
  const float eps = 1e-8f;
  float na = fmaxf(fabsf(s0), eps), nb = fmaxf(fabsf(s1), eps);
  float Wx = (s0 * s1) / (na * nb);
  float Wy = (s1 * s1) / (nb * nb);
  float mx = fmaxf(Wx, Wy);
  float e0 = expf(Wx - mx), e1 = expf(Wy - mx);
  float inv = 1.f / (e0 + e1);
  out[idx] = d0[idx] * (e0 * inv) + d1[idx] * (e1 * inv);
}

// ---------------- split-bf16 MFMA GEMM (128x64 tile) -----------------------
__global__ __launch_bounds__(256) void k_mfma_nt(
    const ushort_t* __restrict__ Ahi, const ushort_t* __restrict__ Alo,
    const ushort_t* __restrict__ Bhi, const ushort_t* __restrict__ Blo,
    float* __restrict__ Cmat, int M, int N, int K, int abatch, int relu,
    int kslices) {
  __shared__ ushort_t AsH[128][40];
  __shared__ ushort_t AsL[128][40];
  __shared__ ushort_t BsH[64][40];
  __shared__ ushort_t BsL[64][40];
  const int zb = blockIdx.z;
  const int b = zb / kslices;
  const int slice = zb - b * kslices;
  const int nch = K >> 5;
  const int cper = (nch + kslices - 1) / kslices;
  const int kbeg = slice * cper * 32;
  const int kend = min(K, kbeg + cper * 32);
  const int n0 = blockIdx.x * 64;
  const int m0 = blockIdx.y * 128;
  const size_t aoff = abatch ? (size_t)b * M * K : (size_t)0;
  const ushort_t* AHp = Ahi + aoff;
  const ushort_t* ALp = Alo + aoff;
  const size_t boff = ((size_t)b * N + n0) * K;
  const ushort_t* BHp = Bhi + boff;
  const ushort_t* BLp = Blo + boff;
  const int t = threadIdx.x;
  const int lane = t & 63;
  const int wv = t >> 6;
  const int wm = wv >> 1, wn = wv & 1;
  const int l15 = lane & 15, quad = lane >> 4;

  const int arow = t >> 1;
  const int acnk = (t & 1) * 2;
  const int brow = t >> 2;
  const int bcnk = t & 3;

  f32x4 acc[4][2];
  const f32x4 z4 = {0.f, 0.f, 0.f, 0.f};
#pragma unroll
  for (int i = 0; i < 4; ++i)
#pragma unroll
    for (int j = 0; j < 2; ++j) acc[i][j] = z4;

  const bool aval = (m0 + arow) < M;
  const uint4 zero16 = {0u, 0u, 0u, 0u};

  for (int k0 = kbeg; k0 < kend; k0 += 32) {
    const size_t arow_off = (size_t)(m0 + arow) * K + k0;
    uint4 ah0 = aval ? *(const uint4*)(AHp + arow_off + acnk * 8) : zero16;
    uint4 ah1 = aval ? *(const uint4*)(AHp + arow_off + (acnk + 1) * 8) : zero16;
    uint4 al0 = aval ? *(const uint4*)(ALp + arow_off + acnk * 8) : zero16;
    uint4 al1 = aval ? *(const uint4*)(ALp + arow_off + (acnk + 1) * 8) : zero16;
    const size_t brow_off = (size_t)brow * K + k0 + bcnk * 8;
    uint4 bh0 = *(const uint4*)(BHp + brow_off);
    uint4 bl0 = *(const uint4*)(BLp + brow_off);
    *(uint4*)&AsH[arow][acnk * 8] = ah0;
    *(uint4*)&AsH[arow][(acnk + 1) * 8] = ah1;
    *(uint4*)&AsL[arow][acnk * 8] = al0;
    *(uint4*)&AsL[arow][(acnk + 1) * 8] = al1;
    *(uint4*)&BsH[brow][bcnk * 8] = bh0;
    *(uint4*)&BsL[brow][bcnk * 8] = bl0;
    __syncthreads();

    bf16x8 afh[4], afl[4], bfh[2], bfl[2];
#pragma unroll
    for (int mt = 0; mt < 4; ++mt) {
      afh[mt] = *(const bf16x8*)&AsH[wm * 64 + mt * 16 + l15][quad * 8];
      afl[mt] = *(const bf16x8*)&AsL[wm * 64 + mt * 16 + l15][quad * 8];
    }
#pragma unroll
    for (int nt = 0; nt < 2; ++nt) {
      bfh[nt] = *(const bf16x8*)&BsH[wn * 32 + nt * 16 + l15][quad * 8];
      bfl[nt] = *(const bf16x8*)&BsL[wn * 32 + nt * 16 + l15][quad * 8];
    }
#pragma unroll
    for (int mt = 0; mt < 4; ++mt)
#pragma unroll
      for (int nt = 0; nt < 2; ++nt) {
        acc[mt][nt] = __builtin_amdgcn_mfma_f32_16x16x32_bf16(
            afh[mt], bfh[nt], acc[mt][nt], 0, 0, 0);
        acc[mt][nt] = __builtin_amdgcn_mfma_f32_16x16x32_bf16(
            afh[mt], bfl[nt], acc[mt][nt], 0, 0, 0);
        acc[mt][nt] = __builtin_amdgcn_mfma_f32_16x16x32_bf16(
            afl[mt], bfh[nt], acc[mt][nt], 0, 0, 0);
      }
    __syncthreads();
  }

  float* Cp = Cmat + (size_t)b * M * N;
#pragma unroll
  for (int mt = 0; mt < 4; ++mt) {
#pragma unroll
    for (int nt = 0; nt < 2; ++nt) {
#pragma unroll
      for (int reg = 0; reg < 4; ++reg) {
        int m = m0 + wm * 64 + mt * 16 + quad * 4 + reg;
        if (m >= M) continue;
        int n = n0 + wn * 32 + nt * 16 + l15;
        if (kslices > 1) {
          atomicAdd(&Cp[(size_t)m * N + n], acc[mt][nt][reg]);
        } else {
          float v = acc[mt][nt][reg];
          if (relu) v = fmaxf(v, 0.f);
          Cp[(size_t)m * N + n] = v;
        }
      }
    }
  }
}

// ---------------- off-conv MFMA: implicit zero-offset im2col (3x3 p1) ------
__global__ __launch_bounds__(256) void k_off_mfma(
    const ushort_t* __restrict__ Ahi, const ushort_t* __restrict__ Alo,
    const float* __restrict__ src, float* __restrict__ Cmat,
    int M, int C, int kslices) {
  const int N = HW;
  const int K = C * 9;
  __shared__ ushort_t BsH[64][40];
  __shared__ ushort_t BsL[64][40];
  __shared__ int spix[64][10];
  const int zb = blockIdx.z;
  const int b = zb / kslices;
  const int slice = zb - b * kslices;
  const int Kc = K / kslices;
  const int kbeg = slice * Kc;
  const int n0 = blockIdx.x * 64;
  const int t = threadIdx.x;
  const int lane = t & 63;
  const int wv = t >> 6;
  const int l15 = lane & 15, quad = lane >> 4;
  const float* sp = src + (size_t)b * C * HW;

  for (int i = t; i < 64 * 9; i += 256) {
    int r = i / 9, q = i - (i / 9) * 9;
    int n = n0 + r;
    int h = n / WWD, w = n - (n / WWD) * WWD;
    int ki = q / 3, kj = q - (q / 3) * 3;
    int y = h - 1 + ki, x = w - 1 + kj;
    spix[r][q] = (y >= 0 && y < HH && x >= 0 && x < WWD) ? (y * WWD + x) : -1;
  }
  __syncthreads();

  const int srow = t >> 2;
  const int scnk = t & 3;

  f32x4 acc[2];
  const f32x4 z4 = {0.f, 0.f, 0.f, 0.f};
  acc[0] = z4;
  acc[1] = z4;
  const uint4 zero16 = {0u, 0u, 0u, 0u};

  for (int k0 = kbeg; k0 < kbeg + Kc; k0 += 32) {
    {
      int k = k0 + scnk * 8;
      int c = k / 9;
      int q = k - c * 9;
#pragma unroll
      for (int j = 0; j < 8; ++j) {
        int ix = spix[srow][q];
        float v = (ix >= 0) ? sp[(size_t)c * HW + ix] : 0.f;
        ushort_t hi, lo;
        split_bf(v, hi, lo);
        BsH[srow][scnk * 8 + j] = hi;
        BsL[srow][scnk * 8 + j] = lo;
        ++q;
        if (q == 9) { q = 0; ++c; }
      }
    }
    __syncthreads();

    bf16x8 afh[2], afl[2], bfh, bfl;
#pragma unroll
    for (int mt = 0; mt < 2; ++mt) {
      int m = mt * 16 + l15;
      bool v = m < M;
      uint4 ah = v ? *(const uint4*)(Ahi + (size_t)m * K + k0 + quad * 8) : zero16;
      uint4 al = v ? *(const uint4*)(Alo + (size_t)m * K + k0 + quad * 8) : zero16;
      afh[mt] = *(const bf16x8*)&ah;
      afl[mt] = *(const bf16x8*)&al;
    }
    bfh = *(const bf16x8*)&BsH[wv * 16 + l15][quad * 8];
    bfl = *(const bf16x8*)&BsL[wv * 16 + l15][quad * 8];
#pragma unroll
    for (int mt = 0; mt < 2; ++mt) {
      acc[mt] = __builtin_amdgcn_mfma_f32_16x16x32_bf16(afh[mt], bfh, acc[mt], 0, 0, 0);
      acc[mt] = __builtin_amdgcn_mfma_f32_16x16x32_bf16(afh[mt], bfl, acc[mt], 0, 0, 0);
      acc[mt] = __builtin_amdgcn_mfma_f32_16x16x32_bf16(afl[mt], bfh, acc[mt], 0, 0, 0);
    }
    __syncthreads();
  }

  float* Cp = Cmat + (size_t)b * M * N;
#pragma unroll
  for (int mt = 0; mt < 2; ++mt)
#pragma unroll
    for (int reg = 0; reg < 4; ++reg) {
      int m = mt * 16 + quad * 4 + reg;
      if (m >= M) continue;
      int n = n0 + wv * 16 + l15;
      atomicAdd(&Cp[(size_t)m * N + n], acc[mt][reg]);
    }
}

// ---------------- split-bf16 M32-tile GEMM over cols -----------------------
__global__ __launch_bounds__(256) void k_gemm_sk(
    const ushort_t* __restrict__ Ahi, const ushort_t* __restrict__ Alo,
    const ushort_t* __restrict__ Bhi, const ushort_t* __restrict__ Blo,
    const float* __restrict__ bias, float* __restrict__ Cmat,
    int M, int N, int Nc, int KP, int kslices, int relu) {
  __shared__ ushort_t BsH[64][40];
  __shared__ ushort_t BsL[64][40];
  const int zb = blockIdx.z;
  const int b = zb / kslices;
  const int slice = zb - b * kslices;
  const int nch = KP >> 5;
  const int cper = (nch + kslices - 1) / kslices;
  const int kbeg = slice * cper * 32;
  const int kend = min(KP, kbeg + cper * 32);
  const int n0 = blockIdx.x * 64;
  const int m0 = blockIdx.y * 32;
  const int t = threadIdx.x;
  const int lane = t & 63;
  const int wv = t >> 6;
  const int l15 = lane & 15, quad = lane >> 4;
  const ushort_t* BHp = Bhi + ((size_t)b * Nc + n0) * KP;
  const ushort_t* BLp = Blo + ((size_t)b * Nc + n0) * KP;
  const int srow = t >> 2, scnk = t & 3;

  f32x4 acc[2];
  const f32x4 z4 = {0.f, 0.f, 0.f, 0.f};
  acc[0] = z4;
  acc[1] = z4;
  const uint4 zero16 = {0u, 0u, 0u, 0u};

  for (int k0 = kbeg; k0 < kend; k0 += 32) {
    const size_t bo = (size_t)srow * KP + k0 + scnk * 8;
    uint4 bh = *(const uint4*)(BHp + bo);
    uint4 bl = *(const uint4*)(BLp + bo);
    *(uint4*)&BsH[srow][scnk * 8] = bh;
    *(uint4*)&BsL[srow][scnk * 8] = bl;
    __syncthreads();

    bf16x8 afh[2], afl[2], bfh, bfl;
#pragma unroll
    for (int mt = 0; mt < 2; ++mt) {
      int m = m0 + mt * 16 + l15;
      bool v = m < M;
      uint4 ah = v ? *(const uint4*)(Ahi + (size_t)m * KP + k0 + quad * 8) : zero16;
      uint4 al = v ? *(const uint4*)(Alo + (size_t)m * KP + k0 + quad * 8) : zero16;
      afh[mt] = *(const bf16x8*)&ah;
      afl[mt] = *(const bf16x8*)&al;
    }
    bfh = *(const bf16x8*)&BsH[wv * 16 + l15][quad * 8];
    bfl = *(const bf16x8*)&BsL[wv * 16 + l15][quad * 8];
#pragma unroll
    for (int mt = 0; mt < 2; ++mt) {
      acc[mt] = __builtin_amdgcn_mfma_f32_16x16x32_bf16(afh[mt], bfh, acc[mt], 0, 0, 0);
      acc[mt] = __builtin_amdgcn_mfma_f32_16x16x32_bf16(afh[mt], bfl, acc[mt], 0, 0, 0);
      acc[mt] = __builtin_amdgcn_mfma_f32_16x16x32_bf16(afl[mt], bfh, acc[mt], 0, 0, 0);
    }
    __syncthreads();
  }

  float* Cp = Cmat + (size_t)b * M * N;
  const int n = n0 + wv * 16 + l15;
  if (n < N) {
#pragma unroll
    for (int mt = 0; mt < 2; ++mt)
#pragma unroll
      for (int reg = 0; reg < 4; ++reg) {
        int m = m0 + mt * 16 + quad * 4 + reg;
        if (m >= M) continue;
        if (kslices > 1) {
          atomicAdd(&Cp[(size_t)m * N + n], acc[mt][reg]);
        } else {
          float v = acc[mt][reg];
          if (bias != nullptr) v += bias[m];
          if (relu) v = fmaxf(v, 0.f);
          Cp[(size_t)m * N + n] = v;
        }
      }
  }
}

// ---------------------------------------------------------------------------

extern "C" void kernel_launch(void* const* d_in, const int* in_sizes, int n_in,
                              void* d_out, int out_size, void* d_ws, size_t ws_size,
                              hipStream_t stream) {
  (void)in_sizes; (void)n_in; (void)out_size;

  const float* R0     = (const float*)d_in[0];
  const float* T0     = (const float*)d_in[1];
  const float* inp    = (const float*)d_in[2];
  const float* enc0_w = (const float*)d_in[3];
  const float* enc0_b = (const float*)d_in[4];
  const float* enc1_w = (const float*)d_in[5];
  const float* enc1_b = (const float*)d_in[6];
  const float* off_w[4] = {(const float*)d_in[7], (const float*)d_in[8],
                           (const float*)d_in[9], (const float*)d_in[10]};
  const float* def_w[3] = {(const float*)d_in[11], (const float*)d_in[12],
                           (const float*)d_in[13]};
  const float* w0a = (const float*)d_in[14];
  const float* w0b = (const float*)d_in[15];
  const float* w0c = (const float*)d_in[16];
  const float* w1a = (const float*)d_in[17];
  const float* w1b = (const float*)d_in[18];
  const float* w1c = (const float*)d_in[19];
  const float* wx_w  = (const float*)d_in[20];
  const float* wx_b  = (const float*)d_in[21];
  const float* wxf_w = (const float*)d_in[22];
  const float* wxf_b = (const float*)d_in[23];
  const float* s1w = (const float*)d_in[24];
  const float* s2w = (const float*)d_in[25];
  const float* s3w = (const float*)d_in[26];

  float* ws = (float*)d_ws;
  size_t used = 0;
  auto alloc = [&](size_t n) { float* p = ws + used; used += n; return p; };
  // xy4 = [x0,x1,y0,y1]; enc4 = [xe0,xe1,ye0,ye1] (contiguous slot tricks)
  float* xy4     = alloc(2359296);   // 4 x 256 x HW
  float* xf      = xy4;
  float* yf      = xy4 + 1179648;
  float* enc4    = alloc(589824);    // 4 x 64 x HW
  float* xenc    = enc4;
  float* yenc    = enc4 + 294912;
  float* featA   = alloc(2359296);   // stsn batch-2
  float* featB   = alloc(2359296);
  float* offb    = alloc(82944);     // 2 x 18 x HW
  float* offsets4= alloc(165888);    // 4 x 18 x HW
  float* featw4  = alloc(1631232);   // 4 x 177 x HW
  float* featw24 = alloc(1631232);
  float* wb1     = alloc(147456);    // 4 x 64 x 576
  float* wb2     = alloc(36864);     // 4 x 64 x 144
  float* wb3     = alloc(36864);     // 4 x 256 x 36 max
  float* fw1     = alloc(1024);      // 4 x 177
  float* fw2     = alloc(1024);      // 4 x 256
  float* deform4 = alloc(2359296);   // 4 x 256 x HW  [d0_0,d0_1,d1_0,d1_1]
  float* sn1     = alloc(1179648);   // 4 x 128 x HW
  float* sn2     = alloc(589824);    // 4 x 64 x HW
  float* sw4     = alloc(9216);      // 4 x HW
  ushort_t *defw_h[3], *defw_l[3];
  for (int i = 0; i < 3; ++i) {
    defw_h[i] = (ushort_t*)alloc(1179648);
    defw_l[i] = (ushort_t*)alloc(1179648);
  }
  ushort_t *offw_h[4], *offw_l[4];
  for (int i = 0; i < 4; ++i) {
    offw_h[i] = (ushort_t*)alloc(41472);
    offw_l[i] = (ushort_t*)alloc(41472);
  }
  ushort_t* wxf_h = (ushort_t*)alloc(1179648);   // 4 x 256 x 2304 u16
  ushort_t* wxf_l = (ushort_t*)alloc(1179648);
  ushort_t* s1w_h = (ushort_t*)alloc(147456);
  ushort_t* s1w_l = (ushort_t*)alloc(147456);
  ushort_t* s2w_h = (ushort_t*)alloc(36864);
  ushort_t* s2w_l = (ushort_t*)alloc(36864);
  ushort_t* w0a_h = (ushort_t*)alloc(144384);
  ushort_t* w0a_l = (ushort_t*)alloc(144384);
  ushort_t* w1a_h = (ushort_t*)alloc(144384);
  ushort_t* w1a_l = (ushort_t*)alloc(144384);
  ushort_t* w0b_h = (ushort_t*)alloc(51200);
  ushort_t* w0b_l = (ushort_t*)alloc(51200);
  ushort_t* w1b_h = (ushort_t*)alloc(51200);
  ushort_t* w1b_l = (ushort_t*)alloc(51200);
  ushort_t* w0c_h = (ushort_t*)alloc(50976);
  ushort_t* w0c_l = (ushort_t*)alloc(50976);
  ushort_t* w1c_h = (ushort_t*)alloc(73728);
  ushort_t* w1c_l = (ushort_t*)alloc(73728);
  ushort_t* e0w_h = (ushort_t*)alloc(8192);
  ushort_t* e0w_l = (ushort_t*)alloc(8192);
  ushort_t* e1w_h = (ushort_t*)alloc(8192);
  ushort_t* e1w_l = (ushort_t*)alloc(8192);
  ushort_t* s3w_h = (ushort_t*)alloc(288);
  ushort_t* s3w_l = (ushort_t*)alloc(288);
  ushort_t* wxad_h = (ushort_t*)alloc(577728);  // 4 x 177 x 1632 u16
  ushort_t* wxad_l = (ushort_t*)alloc(577728);
  ushort_t* cols_h = (ushort_t*)alloc(10616832);
  ushort_t* cols_l = (ushort_t*)alloc(10616832);
  if (used * sizeof(float) > ws_size) return;

  auto mfma = [&](const ushort_t* Ah, const ushort_t* Al, float* Cmat, int M,
                  int K, int abatch, int relu, int ks, int nb) {
    if (ks > 1)
      hipMemsetAsync(Cmat, 0, (size_t)nb * M * 2304 * sizeof(float), stream);
    dim3 grid(2304 / 64, (M + 127) / 128, nb * ks);
    k_mfma_nt<<<grid, 256, 0, stream>>>(Ah, Al, cols_h, cols_l, Cmat, M, 2304, K,
                                        abatch, relu, ks);
  };
  auto off_conv = [&](const ushort_t* Ah, const ushort_t* Al, const float* src,
                      float* Cmat, int C) {
    hipMemsetAsync(Cmat, 0, (size_t)BN * 18 * HW * sizeof(float), stream);
    dim3 grid(36, 1, BN * 8);
    k_off_mfma<<<grid, 256, 0, stream>>>(Ah, Al, src, Cmat, 18, C, 8);
  };
  auto im2col = [&](const float* src, const float* off, int C, int nb) {
    dim3 grid(36, C * 9 / 144, nb);
    if (off == nullptr)
      k_im2col2<1><<<grid, 256, 0, stream>>>(src, nullptr, cols_h, cols_l, C);
    else
      k_im2col2<0><<<grid, 256, 0, stream>>>(src, off, cols_h, cols_l, C);
  };
  auto im2col_g = [&](const float* src, int C, int Hin, int Win, int Hout,
                      int Wout, int Ksz, int stridec, int pad, int KP, int nb) {
    dim3 grid((Hout * Wout + 63) / 64, (C + 3) / 4, nb);
    k_im2col_g<<<grid, 256, 0, stream>>>(src, cols_h, cols_l, C, Hin, Win, Hout,
                                         Wout, Ksz, stridec, pad, KP);
  };
  auto gemm_sk = [&](const ushort_t* Ah, const ushort_t* Al, const float* bias,
                     float* Cmat, int M, int N, int KP, int kslices, int relu,
                     int nb) {
    int Nc = ((N + 63) / 64) * 64;
    if (kslices > 1)
      hipMemsetAsync(Cmat, 0, (size_t)nb * M * N * sizeof(float), stream);
    dim3 grid(Nc / 64, (M + 31) / 32, nb * kslices);
    k_gemm_sk<<<grid, 256, 0, stream>>>(Ah, Al, cols_h, cols_l, bias, Cmat, M,
                                        N, Nc, KP, kslices, relu);
  };

  // ---- weight conversions ----
  for (int i = 0; i < 3; ++i)
    k_w2b<<<(2359296 + 255) / 256, 256, 0, stream>>>(def_w[i], defw_h[i],
                                                     defw_l[i], 2359296);
  for (int i = 0; i < 4; ++i)
    k_w2b<<<(82944 + 255) / 256, 256, 0, stream>>>(off_w[i], offw_h[i],
                                                   offw_l[i], 82944);
  k_w2b<<<(294912 + 255) / 256, 256, 0, stream>>>(s1w, s1w_h, s1w_l, 294912);
  k_w2b<<<(73728 + 255) / 256, 256, 0, stream>>>(s2w, s2w_h, s2w_l, 73728);
  k_w2b_pad<<<(64 * 4512 + 255) / 256, 256, 0, stream>>>(w0a, w0a_h, w0a_l, 64, 4425, 4512);
  k_w2b_pad<<<(64 * 4512 + 255) / 256, 256, 0, stream>>>(w1a, w1a_h, w1a_l, 64, 4425, 4512);
  k_w2b_pad<<<(64 * 1600 + 255) / 256, 256, 0, stream>>>(w0b, w0b_h, w0b_l, 64, 1600, 1600);
  k_w2b_pad<<<(64 * 1600 + 255) / 256, 256, 0, stream>>>(w1b, w1b_h, w1b_l, 64, 1600, 1600);
  k_w2b_pad<<<(177 * 576 + 255) / 256, 256, 0, stream>>>(w0c, w0c_h, w0c_l, 177, 576, 576);
  k_w2b_pad<<<(256 * 576 + 255) / 256, 256, 0, stream>>>(w1c, w1c_h, w1c_l, 256, 576, 576);
  k_w2b_pad<<<(64 * 256 + 255) / 256, 256, 0, stream>>>(enc0_w, e0w_h, e0w_l, 64, 256, 256);
  k_w2b_pad<<<(64 * 256 + 255) / 256, 256, 0, stream>>>(enc1_w, e1w_h, e1w_l, 64, 256, 256);
  k_w2b_pad<<<(576 + 255) / 256, 256, 0, stream>>>(s3w, s3w_h, s3w_l, 1, 576, 576);

  // ---- split + encoders ----
  k_split_xy<<<4608, 256, 0, stream>>>(inp, xf, yf);
  im2col_g(xf, 256, 48, 48, 48, 48, 1, 1, 0, 256, BN);
  gemm_sk(e0w_h, e0w_l, enc0_b, xenc, 64, 2304, 256, 1, 0, BN);
  im2col_g(yf, 256, 48, 48, 48, 48, 1, 1, 0, 256, BN);
  gemm_sk(e1w_h, e1w_l, enc1_b, yenc, 64, 2304, 256, 1, 0, BN);

  // ---- stsn_offset passes (batch-2 each; outputs into offsets4 regions) ----
  auto stsn = [&](const float* srcA, const float* srcB, float* offset_out) {
    k_concat512<<<(BN * 512 * HW) / 256, 256, 0, stream>>>(srcA, srcB, featA);
    float* cur = featA;
    float* nxt = featB;
    for (int i = 0; i < 3; ++i) {
      off_conv(offw_h[i], offw_l[i], cur, offb, 512);
      im2col(cur, offb, 512, BN);
      mfma(defw_h[i], defw_l[i], nxt, 512, 4608, 0, 0, 4, BN);
      float* tmp = cur; cur = nxt; nxt = tmp;
    }
    off_conv(offw_h[3], offw_l[3], cur, offset_out, 512);
  };
  stsn(xf, yf, offsets4);
  stsn(yf, yf, offsets4 + 2 * 18 * HW);

  // ---- astsn_weight + adaptive deform conv (batch-4 across both passes) ----
  auto branch = [&](const float* fin, const ushort_t* wah, const ushort_t* wal,
                    const ushort_t* wbh, const ushort_t* wbl,
                    const ushort_t* wch, const ushort_t* wcl, int Mout,
                    float* fwout) {
    im2col_g(fin, 177, 48, 48, 24, 24, 5, 2, 2, 4512, 4);
    gemm_sk(wah, wal, nullptr, wb1, 64, 576, 4512, 8, 0, 4);
    k_relu<<<(4 * 64 * 576 + 255) / 256, 256, 0, stream>>>(wb1, 4 * 64 * 576);
    im2col_g(wb1, 64, 24, 24, 12, 12, 5, 2, 2, 1600, 4);
    gemm_sk(wbh, wbl, nullptr, wb2, 64, 144, 1600, 4, 0, 4);
    k_relu<<<(4 * 64 * 144 + 255) / 256, 256, 0, stream>>>(wb2, 4 * 64 * 144);
    im2col_g(wb2, 64, 12, 12, 6, 6, 3, 2, 1, 576, 4);
    gemm_sk(wch, wcl, nullptr, wb3, Mout, 36, 576, 2, 0, 4);
    k_mean<<<(4 * Mout + 255) / 256, 256, 0, stream>>>(wb3, fwout, 4 * Mout, 36);
  };

  k_correlation4<<<(4 * 49 * HW + 255) / 256, 256, 0, stream>>>(R0, T0, featw4);
  k_pack_enc4<<<(4 * 64 * HW + 255) / 256, 256, 0, stream>>>(enc4, featw4);
  branch(featw4, w0a_h, w0a_l, w0b_h, w0b_l, w0c_h, w0c_l, 177, fw1);
  k_w2b_fw_pad<<<(4 * 177 * 1632 + 255) / 256, 256, 0, stream>>>(
      wx_w, wx_b, fw1, wxad_h, wxad_l, 177, 1593, 1632, 4);
  im2col_g(featw4, 177, 48, 48, 48, 48, 3, 1, 1, 1632, 4);
  mfma(wxad_h, wxad_l, featw24, 177, 1632, 1, 0, 2, 4);
  k_relu<<<(4 * 177 * HW + 255) / 256, 256, 0, stream>>>(featw24, 4 * 177 * HW);
  branch(featw24, w1a_h, w1a_l, w1b_h, w1b_l, w1c_h, w1c_l, 256, fw2);
  k_w2b_fw<<<(4 * 256 * 2304 + 255) / 256, 256, 0, stream>>>(
      wxf_w, wxf_b, fw2, wxf_h, wxf_l, 256, 2304, 4);
  im2col(xy4, offsets4, 256, 4);
  mfma(wxf_h, wxf_l, deform4, 256, 2304, 1, 0, 2, 4);

  // ---- s_net (batch-4) ----
  im2col(deform4, nullptr, 256, 4);
  mfma(s1w_h, s1w_l, sn1, 128, 2304, 0, 0, 4, 4);
  k_relu<<<(4 * 128 * HW + 255) / 256, 256, 0, stream>>>(sn1, 4 * 128 * HW);
  im2col(sn1, nullptr, 128, 4);
  mfma(s2w_h, s2w_l, sn2, 64, 1152, 0, 0, 4, 4);
  k_relu<<<(4 * 64 * HW + 255) / 256, 256, 0, stream>>>(sn2, 4 * 64 * HW);
  im2col_g(sn2, 64, 48, 48, 48, 48, 3, 1, 1, 576, 4);
  gemm_sk(s3w_h, s3w_l, nullptr, sw4, 1, 2304, 576, 1, 1, 4);

  // ---- blend ----
  k_blend<<<4608, 256, 0, stream>>>(deform4, deform4 + 2 * 256 * HW, sw4,
                                    sw4 + 2 * HW, (float*)d_out);
}

// Round 13
// 2406.153 us; speedup vs baseline: 1.1434x; 1.0086x over previous
//
#include <hip/hip_runtime.h>
#include <stdint.h>

// ---------------------------------------------------------------------------
// Round 13: batch-4 stsn (two independent chains merged per-layer via xy4
// slot trick) when ws_size permits (+104 MB cols); runtime fallback to the
// r12-proven batch-2 stsn otherwise. Weight conversions merged 15 -> 8
// launches. astsn/s_net batch-4 and all GEMM kernels as r12.
// ---------------------------------------------------------------------------

typedef unsigned short ushort_t;
typedef __attribute__((ext_vector_type(8))) short bf16x8;
typedef __attribute__((ext_vector_type(4))) float f32x4;

#define BN 2
#define HH 48
#define WWD 48
#define HW 2304

__device__ __forceinline__ float b2f(ushort_t h) {
  union { uint32_t u; float f; } v; v.u = ((uint32_t)h) << 16; return v.f;
}
__device__ __forceinline__ ushort_t f2b(float f) {
  union { float f; uint32_t u; } v; v.f = f;
  uint32_t u = v.u;
  uint32_t r = (u + 0x7fffu + ((u >> 16) & 1u)) >> 16;
  return (ushort_t)r;
}
__device__ __forceinline__ void split_bf(float v, ushort_t& hi, ushort_t& lo) {
  hi = f2b(v);
  lo = f2b(v - b2f(hi));
}

// ---------------- elementwise / packing kernels ----------------------------

__global__ void k_split_xy(const float* __restrict__ in, float* __restrict__ xf,
                           float* __restrict__ yf) {
  int idx = blockIdx.x * blockDim.x + threadIdx.x;
  const int tot = BN * 256 * HW;
  if (idx >= tot) return;
  int b = idx / (256 * HW);
  int r = idx - b * (256 * HW);
  xf[idx] = in[(size_t)(2 * b) * (256 * HW) + r];
  yf[idx] = in[(size_t)(2 * b + 1) * (256 * HW) + r];
}

__global__ void k_concat512(const float* __restrict__ a, const float* __restrict__ c2,
                            float* __restrict__ feat) {
  int idx = blockIdx.x * blockDim.x + threadIdx.x;
  const int tot = BN * 512 * HW;
  if (idx >= tot) return;
  int b = idx / (512 * HW);
  int r = idx - b * (512 * HW);
  int c = r / HW;
  int n = r - c * HW;
  feat[idx] = (c < 256) ? a[(b * 256 + c) * HW + n]
                        : c2[(b * 256 + (c - 256)) * HW + n];
}

// batch-4 concat: feat4[bb] = concat(xy4[bb], xy4[2+(bb&1)])
__global__ void k_concat512_4(const float* __restrict__ xy4,
                              float* __restrict__ feat) {
  int idx = blockIdx.x * blockDim.x + threadIdx.x;
  const int tot = 4 * 512 * HW;
  if (idx >= tot) return;
  int bb = idx / (512 * HW);
  int r = idx - bb * (512 * HW);
  int c = r / HW;
  int n = r - c * HW;
  feat[idx] = (c < 256)
                  ? xy4[((size_t)bb * 256 + c) * HW + n]
                  : xy4[((size_t)(2 + (bb & 1)) * 256 + (c - 256)) * HW + n];
}

__global__ void k_relu(float* __restrict__ p, int n) {
  int idx = blockIdx.x * blockDim.x + threadIdx.x;
  if (idx < n) p[idx] = fmaxf(p[idx], 0.f);
}

__global__ void k_mean(const float* __restrict__ src, float* __restrict__ dst,
                       int Mtot, int N) {
  int idx = blockIdx.x * blockDim.x + threadIdx.x;
  if (idx >= Mtot) return;
  const float* p = src + (size_t)idx * N;
  float s = 0.f;
  for (int i = 0; i < N; ++i) s += p[i];
  dst[idx] = s / (float)N;
}

__global__ void k_w2b(const float* __restrict__ w, ushort_t* __restrict__ ohi,
                      ushort_t* __restrict__ olo, int n) {
  int idx = blockIdx.x * blockDim.x + threadIdx.x;
  if (idx < n) split_bf(w[idx], ohi[idx], olo[idx]);
}

// z-merged conversions (same element count per z)
__global__ void k_w2bz3(const float* __restrict__ p0, const float* __restrict__ p1,
                        const float* __restrict__ p2, ushort_t* __restrict__ h0,
                        ushort_t* __restrict__ h1, ushort_t* __restrict__ h2,
                        ushort_t* __restrict__ l0, ushort_t* __restrict__ l1,
                        ushort_t* __restrict__ l2, int n) {
  int idx = blockIdx.x * blockDim.x + threadIdx.x;
  if (idx >= n) return;
  int z = blockIdx.z;
  const float* p = (z == 0) ? p0 : (z == 1) ? p1 : p2;
  ushort_t* h = (z == 0) ? h0 : (z == 1) ? h1 : h2;
  ushort_t* l = (z == 0) ? l0 : (z == 1) ? l1 : l2;
  split_bf(p[idx], h[idx], l[idx]);
}

__global__ void k_w2bz4(const float* __restrict__ p0, const float* __restrict__ p1,
                        const float* __restrict__ p2, const float* __restrict__ p3,
                        ushort_t* __restrict__ h0, ushort_t* __restrict__ h1,
                        ushort_t* __restrict__ h2, ushort_t* __restrict__ h3,
                        ushort_t* __restrict__ l0, ushort_t* __restrict__ l1,
                        ushort_t* __restrict__ l2, ushort_t* __restrict__ l3,
                        int n) {
  int idx = blockIdx.x * blockDim.x + threadIdx.x;
  if (idx >= n) return;
  int z = blockIdx.z;
  const float* p = (z == 0) ? p0 : (z == 1) ? p1 : (z == 2) ? p2 : p3;
  ushort_t* h = (z == 0) ? h0 : (z == 1) ? h1 : (z == 2) ? h2 : h3;
  ushort_t* l = (z == 0) ? l0 : (z == 1) ? l1 : (z == 2) ? l2 : l3;
  split_bf(p[idx], h[idx], l[idx]);
}

__global__ void k_w2b_pad(const float* __restrict__ w, ushort_t* __restrict__ ohi,
                          ushort_t* __restrict__ olo, int M, int K, int Kpad) {
  int idx = blockIdx.x * blockDim.x + threadIdx.x;
  if (idx >= M * Kpad) return;
  int m = idx / Kpad, k = idx - m * Kpad;
  float v = (k < K) ? w[(size_t)m * K + k] : 0.f;
  split_bf(v, ohi[idx], olo[idx]);
}

__global__ void k_w2b_padz2(const float* __restrict__ p0, const float* __restrict__ p1,
                            ushort_t* __restrict__ h0, ushort_t* __restrict__ h1,
                            ushort_t* __restrict__ l0, ushort_t* __restrict__ l1,
                            int M0, int M1, int K, int Kpad) {
  int idx = blockIdx.x * blockDim.x + threadIdx.x;
  int z = blockIdx.z;
  int M = z ? M1 : M0;
  if (idx >= M * Kpad) return;
  int m = idx / Kpad, k = idx - m * Kpad;
  const float* w = z ? p1 : p0;
  ushort_t* h = z ? h1 : h0;
  ushort_t* l = z ? l1 : l0;
  float v = (k < K) ? w[(size_t)m * K + k] : 0.f;
  split_bf(v, h[idx], l[idx]);
}

__global__ void k_w2b_fw(const float* __restrict__ w, const float* __restrict__ wb,
                         const float* __restrict__ fw, ushort_t* __restrict__ ohi,
                         ushort_t* __restrict__ olo, int M, int K, int NB) {
  int idx = blockIdx.x * blockDim.x + threadIdx.x;
  int tot = NB * M * K;
  if (idx >= tot) return;
  int b = idx / (M * K);
  int r = idx - b * (M * K);
  int m = r / K;
  split_bf(fw[b * M + m] * w[r] + wb[r], ohi[idx], olo[idx]);
}

__global__ void k_w2b_fw_pad(const float* __restrict__ w, const float* __restrict__ wb,
                             const float* __restrict__ fw, ushort_t* __restrict__ ohi,
                             ushort_t* __restrict__ olo, int M, int K, int Kpad,
                             int NB) {
  int idx = blockIdx.x * blockDim.x + threadIdx.x;
  int tot = NB * M * Kpad;
  if (idx >= tot) return;
  int b = idx / (M * Kpad);
  int r = idx - b * (M * Kpad);
  int m = r / Kpad;
  int k = r - m * Kpad;
  float v = 0.f;
  if (k < K) v = fw[b * M + m] * w[(size_t)m * K + k] + wb[(size_t)m * K + k];
  split_bf(v, ohi[idx], olo[idx]);
}

__global__ void k_correlation4(const float* __restrict__ R0,
                               const float* __restrict__ T0,
                               float* __restrict__ featw) {
  int idx = blockIdx.x * blockDim.x + threadIdx.x;
  const int tot = 4 * 49 * HW;
  if (idx >= tot) return;
  int n = idx % HW;
  int t = idx / HW;
  int d = t % 49;
  int bb = t / 49;
  int pass = bb >> 1, b = bb & 1;
  int dyi = d / 7, dxi = d - dyi * 7;
  int dy = 2 * (dyi - 3), dx = 2 * (dxi - 3);
  int h = n / WWD, w = n - h * WWD;
  int hb = h + dy, wb = w + dx;
  float s = 0.f;
  if (hb >= 0 && hb < HH && wb >= 0 && wb < WWD) {
    const float* ap = R0 + ((size_t)(b * 2 + pass) * 64) * HW + n;
    const float* bp = T0 + ((size_t)(b * 2 + 1) * 64) * HW + hb * WWD + wb;
#pragma unroll 8
    for (int c = 0; c < 64; ++c) s += ap[(size_t)c * HW] * bp[(size_t)c * HW];
  }
  featw[((size_t)bb * 177 + d) * HW + n] = s * (1.f / 64.f);
}

__global__ void k_pack_enc4(const float* __restrict__ enc4,
                            float* __restrict__ featw) {
  int idx = blockIdx.x * blockDim.x + threadIdx.x;
  const int tot = 4 * 64 * HW;
  if (idx >= tot) return;
  int bb = idx / (64 * HW);
  int r = idx - bb * (64 * HW);
  featw[((size_t)bb * 177 + 49) * HW + r] = enc4[(size_t)bb * 64 * HW + r];
  featw[((size_t)bb * 177 + 113) * HW + r] =
      enc4[(size_t)(2 + (bb & 1)) * 64 * HW + r];
}

// ---------------- im2col v2 (3x3 pad1 on 48x48, deform/zero) ---------------
template <int ZERO>
__global__ __launch_bounds__(256) void k_im2col2(
    const float* __restrict__ src, const float* __restrict__ off,
    ushort_t* __restrict__ dhi, ushort_t* __restrict__ dlo, int C) {
  __shared__ ushort_t LH[64][152];
  __shared__ ushort_t LL[64][152];
  const int b = blockIdx.z;
  const int t = threadIdx.x;
  const int nloc = t >> 2;
  const int csub = t & 3;
  const int n = blockIdx.x * 64 + nloc;
  const int c0 = blockIdx.y * 16 + csub * 4;
  const int K = C * 9;
  const int h = n / WWD, w = n - (n / WWD) * WWD;
  const float* sp = src + (size_t)b * C * HW;

  float wgt[9][4];
  int sid[9][4];
  if (ZERO) {
#pragma unroll
    for (int q = 0; q < 9; ++q) {
      int ki = q / 3, kj = q - (q / 3) * 3;
      int y = h - 1 + ki, x = w - 1 + kj;
      bool v = (y >= 0 && y < HH && x >= 0 && x < WWD);
      sid[q][0] = v ? y * WWD + x : 0;
      wgt[q][0] = v ? 1.f : 0.f;
    }
  } else {
#pragma unroll
    for (int q = 0; q < 9; ++q) {
      int ki = q / 3, kj = q - (q / 3) * 3;
      float dy = off[((size_t)(b * 9 + q) * 2 + 0) * HW + n];
      float dx = off[((size_t)(b * 9 + q) * 2 + 1) * HW + n];
      float py = (float)(h - 1 + ki) + dy;
      float px = (float)(w - 1 + kj) + dx;
      float fy = floorf(py), fx = floorf(px);
      float ay = py - fy, ax = px - fx;
      int y0 = (int)fy, x0 = (int)fx;
      int y1 = y0 + 1, x1 = x0 + 1;
      float w00 = (1.f - ay) * (1.f - ax), w01 = (1.f - ay) * ax;
      float w10 = ay * (1.f - ax), w11 = ay * ax;
      bool vy0 = (y0 >= 0 && y0 < HH), vy1 = (y1 >= 0 && y1 < HH);
      bool vx0 = (x0 >= 0 && x0 < WWD), vx1 = (x1 >= 0 && x1 < WWD);
      int cy0 = min(max(y0, 0), HH - 1), cy1 = min(max(y1, 0), HH - 1);
      int cx0 = min(max(x0, 0), WWD - 1), cx1 = min(max(x1, 0), WWD - 1);
      sid[q][0] = cy0 * WWD + cx0;
      sid[q][1] = cy0 * WWD + cx1;
      sid[q][2] = cy1 * WWD + cx0;
      sid[q][3] = cy1 * WWD + cx1;
      wgt[q][0] = (vy0 && vx0) ? w00 : 0.f;
      wgt[q][1] = (vy0 && vx1) ? w01 : 0.f;
      wgt[q][2] = (vy1 && vx0) ? w10 : 0.f;
      wgt[q][3] = (vy1 && vx1) ? w11 : 0.f;
    }
  }

#pragma unroll
  for (int cc = 0; cc < 4; ++cc) {
    int c = c0 + cc;
    const float* s = sp + (size_t)c * HW;
    int kb = (csub * 4 + cc) * 9;
#pragma unroll
    for (int q = 0; q < 9; ++q) {
      float v;
      if (ZERO)
        v = wgt[q][0] * s[sid[q][0]];
      else
        v = wgt[q][0] * s[sid[q][0]] + wgt[q][1] * s[sid[q][1]] +
            wgt[q][2] * s[sid[q][2]] + wgt[q][3] * s[sid[q][3]];
      ushort_t hi, lo;
      split_bf(v, hi, lo);
      LH[nloc][kb + q] = hi;
      LL[nloc][kb + q] = lo;
    }
  }
  __syncthreads();

  const size_t rowbase = (size_t)b * HW + blockIdx.x * 64;
  const int kt0 = blockIdx.y * 144;
  for (int idx = t; idx < 64 * 18; idx += 256) {
    int r = idx / 18, ch = idx - (idx / 18) * 18;
    uint4 vh = *(const uint4*)&LH[r][ch * 8];
    uint4 vl = *(const uint4*)&LL[r][ch * 8];
    size_t g = (rowbase + r) * K + kt0 + ch * 8;
    *(uint4*)(dhi + g) = vh;
    *(uint4*)(dlo + g) = vl;
  }
}

// ---------------- general im2col (any Ksz<=5/stride/pad, zero-offset) ------
__global__ __launch_bounds__(256) void k_im2col_g(
    const float* __restrict__ src, ushort_t* __restrict__ dhi,
    ushort_t* __restrict__ dlo, int C, int Hin, int Win, int Hout, int Wout,
    int Ksz, int stride, int pad, int KP) {
  __shared__ ushort_t LH[64][100];
  __shared__ ushort_t LL[64][100];
  const int b = blockIdx.z;
  const int t = threadIdx.x;
  const int nloc = t >> 2, csub = t & 3;
  const int n0 = blockIdx.x * 64;
  const int n = n0 + nloc;
  const int c = blockIdx.y * 4 + csub;
  const int N = Hout * Wout;
  const int K2 = Ksz * Ksz;
  const int h = n / Wout, w = n - (n / Wout) * Wout;
  const bool val = (c < C) && (n < N);
  const float* s = src + ((size_t)b * C + c) * Hin * Win;
  for (int q = 0; q < K2; ++q) {
    int ki = q / Ksz, kj = q - (q / Ksz) * Ksz;
    int y = h * stride + ki - pad, x = w * stride + kj - pad;
    float v = 0.f;
    if (val && y >= 0 && y < Hin && x >= 0 && x < Win) v = s[y * Win + x];
    ushort_t hi, lo;
    split_bf(v, hi, lo);
    LH[nloc][csub * K2 + q] = hi;
    LL[nloc][csub * K2 + q] = lo;
  }
  __syncthreads();
  const int Nc = gridDim.x * 64;
  const int rl = 4 * K2;
  const int kt0 = blockIdx.y * rl;
  const int nu2 = rl >> 2;
  for (int idx = t; idx < 64 * nu2; idx += 256) {
    int r = idx / nu2, ch = idx - (idx / nu2) * nu2;
    uint2 vh = *(const uint2*)&LH[r][ch * 4];
    uint2 vl = *(const uint2*)&LL[r][ch * 4];
    size_t g = ((size_t)b * Nc + n0 + r) * KP + kt0 + ch * 4;
    *(uint2*)(dhi + g) = vh;
    *(uint2*)(dlo + g) = vl;
  }
}

__global__ void k_blend(const float* __restrict__ d0, const float* __restrict__ d1,
                        const float* __restrict__ sw0, const float* __restrict__ sw1,
                        float* __restrict__ out) {
  int idx = blockIdx.x * blockDim.x + threadIdx.x;
  const int tot = BN * 256 * HW;
  if (idx >= tot) return;
  int b = idx / (256 * HW);
  int n = idx % HW;
  float s0 = sw0[b * HW + n], s1 = sw1[b * HW + n];
  const float eps = 1e-8f;
  float na = fmaxf(fabsf(s0), eps), nb = fmaxf(fabsf(s1), eps);
  float Wx = (s0 * s1) / (na * nb);
  float Wy = (s1 * s1) / (nb * nb);
  float mx = fmaxf(Wx, Wy);
  float e0 = expf(Wx - mx), e1 = expf(Wy - mx);
  float inv = 1.f / (e0 + e1);
  out[idx] = d0[idx] * (e0 * inv) + d1[idx] * (e1 * inv);
}

// ---------------- split-bf16 MFMA GEMM (128x64 tile) -----------------------
__global__ __launch_bounds__(256) void k_mfma_nt(
    const ushort_t* __restrict__ Ahi, const ushort_t* __restrict__ Alo,
    const ushort_t* __restrict__ Bhi, const ushort_t* __restrict__ Blo,
    float* __restrict__ Cmat, int M, int N, int K, int abatch, int relu,
    int kslices) {
  __shared__ ushort_t AsH[128][40];
  __shared__ ushort_t AsL[128][40];
  __shared__ ushort_t BsH[64][40];
  __shared__ ushort_t BsL[64][40];
  const int zb = blockIdx.z;
  const int b = zb / kslices;
  const int slice = zb - b * kslices;
  const int nch = K >> 5;
  const int cper = (nch + kslices - 1) / kslices;
  const int kbeg = slice * cper * 32;
  const int kend = min(K, kbeg + cper * 32);
  const int n0 = blockIdx.x * 64;
  const int m0 = blockIdx.y * 128;
  const size_t aoff = abatch ? (size_t)b * M * K : (size_t)0;
  const ushort_t* AHp = Ahi + aoff;
  const ushort_t* ALp = Alo + aoff;
  const size_t boff = ((size_t)b * N + n0) * K;
  const ushort_t* BHp = Bhi + boff;
  const ushort_t* BLp = Blo + boff;
  const int t = threadIdx.x;
  const int lane = t & 63;
  const int wv = t >> 6;
  const int wm = wv >> 1, wn = wv & 1;
  const int l15 = lane & 15, quad = lane >> 4;

  const int arow = t >> 1;
  const int acnk = (t & 1) * 2;
  const int brow = t >> 2;
  const int bcnk = t & 3;

  f32x4 acc[4][2];
  const f32x4 z4 = {0.f, 0.f, 0.f, 0.f};
#pragma unroll
  for (int i = 0; i < 4; ++i)
#pragma unroll
    for (int j = 0; j < 2; ++j) acc[i][j] = z4;

  const bool aval = (m0 + arow) < M;
  const uint4 zero16 = {0u, 0u, 0u, 0u};

  for (int k0 = kbeg; k0 < kend; k0 += 32) {
    const size_t arow_off = (size_t)(m0 + arow) * K + k0;
    uint4 ah0 = aval ? *(const uint4*)(AHp + arow_off + acnk * 8) : zero16;
    uint4 ah1 = aval ? *(const uint4*)(AHp + arow_off + (acnk + 1) * 8) : zero16;
    uint4 al0 = aval ? *(const uint4*)(ALp + arow_off + acnk * 8) : zero16;
    uint4 al1 = aval ? *(const uint4*)(ALp + arow_off + (acnk + 1) * 8) : zero16;
    const size_t brow_off = (size_t)brow * K + k0 + bcnk * 8;
    uint4 bh0 = *(const uint4*)(BHp + brow_off);
    uint4 bl0 = *(const uint4*)(BLp + brow_off);
    *(uint4*)&AsH[arow][acnk * 8] = ah0;
    *(uint4*)&AsH[arow][(acnk + 1) * 8] = ah1;
    *(uint4*)&AsL[arow][acnk * 8] = al0;
    *(uint4*)&AsL[arow][(acnk + 1) * 8] = al1;
    *(uint4*)&BsH[brow][bcnk * 8] = bh0;
    *(uint4*)&BsL[brow][bcnk * 8] = bl0;
    __syncthreads();

    bf16x8 afh[4], afl[4], bfh[2], bfl[2];
#pragma unroll
    for (int mt = 0; mt < 4; ++mt) {
      afh[mt] = *(const bf16x8*)&AsH[wm * 64 + mt * 16 + l15][quad * 8];
      afl[mt] = *(const bf16x8*)&AsL[wm * 64 + mt * 16 + l15][quad * 8];
    }
#pragma unroll
    for (int nt = 0; nt < 2; ++nt) {
      bfh[nt] = *(const bf16x8*)&BsH[wn * 32 + nt * 16 + l15][quad * 8];
      bfl[nt] = *(const bf16x8*)&BsL[wn * 32 + nt * 16 + l15][quad * 8];
    }
#pragma unroll
    for (int mt = 0; mt < 4; ++mt)
#pragma unroll
      for (int nt = 0; nt < 2; ++nt) {
        acc[mt][nt] = __builtin_amdgcn_mfma_f32_16x16x32_bf16(
            afh[mt], bfh[nt], acc[mt][nt], 0, 0, 0);
        acc[mt][nt] = __builtin_amdgcn_mfma_f32_16x16x32_bf16(
            afh[mt], bfl[nt], acc[mt][nt], 0, 0, 0);
        acc[mt][nt] = __builtin_amdgcn_mfma_f32_16x16x32_bf16(
            afl[mt], bfh[nt], acc[mt][nt], 0, 0, 0);
      }
    __syncthreads();
  }

  float* Cp = Cmat + (size_t)b * M * N;
#pragma unroll
  for (int mt = 0; mt < 4; ++mt) {
#pragma unroll
    for (int nt = 0; nt < 2; ++nt) {
#pragma unroll
      for (int reg = 0; reg < 4; ++reg) {
        int m = m0 + wm * 64 + mt * 16 + quad * 4 + reg;
        if (m >= M) continue;
        int n = n0 + wn * 32 + nt * 16 + l15;
        if (kslices > 1) {
          atomicAdd(&Cp[(size_t)m * N + n], acc[mt][nt][reg]);
        } else {
          float v = acc[mt][nt][reg];
          if (relu) v = fmaxf(v, 0.f);
          Cp[(size_t)m * N + n] = v;
        }
      }
    }
  }
}

// ---------------- off-conv MFMA: implicit zero-offset im2col (3x3 p1) ------
__global__ __launch_bounds__(256) void k_off_mfma(
    const ushort_t* __restrict__ Ahi, const ushort_t* __restrict__ Alo,
    const float* __restrict__ src, float* __restrict__ Cmat,
    int M, int C, int kslices) {
  const int N = HW;
  const int K = C * 9;
  __shared__ ushort_t BsH[64][40];
  __shared__ ushort_t BsL[64][40];
  __shared__ int spix[64][10];
  const int zb = blockIdx.z;
  const int b = zb / kslices;
  const int slice = zb - b * kslices;
  const int Kc = K / kslices;
  const int kbeg = slice * Kc;
  const int n0 = blockIdx.x * 64;
  const int t = threadIdx.x;
  const int lane = t & 63;
  const int wv = t >> 6;
  const int l15 = lane & 15, quad = lane >> 4;
  const float* sp = src + (size_t)b * C * HW;

  for (int i = t; i < 64 * 9; i += 256) {
    int r = i / 9, q = i - (i / 9) * 9;
    int n = n0 + r;
    int h = n / WWD, w = n - (n / WWD) * WWD;
    int ki = q / 3, kj = q - (q / 3) * 3;
    int y = h - 1 + ki, x = w - 1 + kj;
    spix[r][q] = (y >= 0 && y < HH && x >= 0 && x < WWD) ? (y * WWD + x) : -1;
  }
  __syncthreads();

  const int srow = t >> 2;
  const int scnk = t & 3;

  f32x4 acc[2];
  const f32x4 z4 = {0.f, 0.f, 0.f, 0.f};
  acc[0] = z4;
  acc[1] = z4;
  const uint4 zero16 = {0u, 0u, 0u, 0u};

  for (int k0 = kbeg; k0 < kbeg + Kc; k0 += 32) {
    {
      int k = k0 + scnk * 8;
      int c = k / 9;
      int q = k - c * 9;
#pragma unroll
      for (int j = 0; j < 8; ++j) {
        int ix = spix[srow][q];
        float v = (ix >= 0) ? sp[(size_t)c * HW + ix] : 0.f;
        ushort_t hi, lo;
        split_bf(v, hi, lo);
        BsH[srow][scnk * 8 + j] = hi;
        BsL[srow][scnk * 8 + j] = lo;
        ++q;
        if (q == 9) { q = 0; ++c; }
      }
    }
    __syncthreads();

    bf16x8 afh[2], afl[2], bfh, bfl;
#pragma unroll
    for (int mt = 0; mt < 2; ++mt) {
      int m = mt * 16 + l15;
      bool v = m < M;
      uint4 ah = v ? *(const uint4*)(Ahi + (size_t)m * K + k0 + quad * 8) : zero16;
      uint4 al = v ? *(const uint4*)(Alo + (size_t)m * K + k0 + quad * 8) : zero16;
      afh[mt] = *(const bf16x8*)&ah;
      afl[mt] = *(const bf16x8*)&al;
    }
    bfh = *(const bf16x8*)&BsH[wv * 16 + l15][quad * 8];
    bfl = *(const bf16x8*)&BsL[wv * 16 + l15][quad * 8];
#pragma unroll
    for (int mt = 0; mt < 2; ++mt) {
      acc[mt] = __builtin_amdgcn_mfma_f32_16x16x32_bf16(afh[mt], bfh, acc[mt], 0, 0, 0);
      acc[mt] = __builtin_amdgcn_mfma_f32_16x16x32_bf16(afh[mt], bfl, acc[mt], 0, 0, 0);
      acc[mt] = __builtin_amdgcn_mfma_f32_16x16x32_bf16(afl[mt], bfh, acc[mt], 0, 0, 0);
    }
    __syncthreads();
  }

  float* Cp = Cmat + (size_t)b * M * N;
#pragma unroll
  for (int mt = 0; mt < 2; ++mt)
#pragma unroll
    for (int reg = 0; reg < 4; ++reg) {
      int m = mt * 16 + quad * 4 + reg;
      if (m >= M) continue;
      int n = n0 + wv * 16 + l15;
      atomicAdd(&Cp[(size_t)m * N + n], acc[mt][reg]);
    }
}

// ---------------- split-bf16 M32-tile GEMM over cols -----------------------
__global__ __launch_bounds__(256) void k_gemm_sk(
    const ushort_t* __restrict__ Ahi, const ushort_t* __restrict__ Alo,
    const ushort_t* __restrict__ Bhi, const ushort_t* __restrict__ Blo,
    const float* __restrict__ bias, float* __restrict__ Cmat,
    int M, int N, int Nc, int KP, int kslices, int relu) {
  __shared__ ushort_t BsH[64][40];
  __shared__ ushort_t BsL[64][40];
  const int zb = blockIdx.z;
  const int b = zb / kslices;
  const int slice = zb - b * kslices;
  const int nch = KP >> 5;
  const int cper = (nch + kslices - 1) / kslices;
  const int kbeg = slice * cper * 32;
  const int kend = min(KP, kbeg + cper * 32);
  const int n0 = blockIdx.x * 64;
  const int m0 = blockIdx.y * 32;
  const int t = threadIdx.x;
  const int lane = t & 63;
  const int wv = t >> 6;
  const int l15 = lane & 15, quad = lane >> 4;
  const ushort_t* BHp = Bhi + ((size_t)b * Nc + n0) * KP;
  const ushort_t* BLp = Blo + ((size_t)b * Nc + n0) * KP;
  const int srow = t >> 2, scnk = t & 3;

  f32x4 acc[2];
  const f32x4 z4 = {0.f, 0.f, 0.f, 0.f};
  acc[0] = z4;
  acc[1] = z4;
  const uint4 zero16 = {0u, 0u, 0u, 0u};

  for (int k0 = kbeg; k0 < kend; k0 += 32) {
    const size_t bo = (size_t)srow * KP + k0 + scnk * 8;
    uint4 bh = *(const uint4*)(BHp + bo);
    uint4 bl = *(const uint4*)(BLp + bo);
    *(uint4*)&BsH[srow][scnk * 8] = bh;
    *(uint4*)&BsL[srow][scnk * 8] = bl;
    __syncthreads();

    bf16x8 afh[2], afl[2], bfh, bfl;
#pragma unroll
    for (int mt = 0; mt < 2; ++mt) {
      int m = m0 + mt * 16 + l15;
      bool v = m < M;
      uint4 ah = v ? *(const uint4*)(Ahi + (size_t)m * KP + k0 + quad * 8) : zero16;
      uint4 al = v ? *(const uint4*)(Alo + (size_t)m * KP + k0 + quad * 8) : zero16;
      afh[mt] = *(const bf16x8*)&ah;
      afl[mt] = *(const bf16x8*)&al;
    }
    bfh = *(const bf16x8*)&BsH[wv * 16 + l15][quad * 8];
    bfl = *(const bf16x8*)&BsL[wv * 16 + l15][quad * 8];
#pragma unroll
    for (int mt = 0; mt < 2; ++mt) {
      acc[mt] = __builtin_amdgcn_mfma_f32_16x16x32_bf16(afh[mt], bfh, acc[mt], 0, 0, 0);
      acc[mt] = __builtin_amdgcn_mfma_f32_16x16x32_bf16(afh[mt], bfl, acc[mt], 0, 0, 0);
      acc[mt] = __builtin_amdgcn_mfma_f32_16x16x32_bf16(afl[mt], bfh, acc[mt], 0, 0, 0);
    }
    __syncthreads();
  }

  float* Cp = Cmat + (size_t)b * M * N;
  const int n = n0 + wv * 16 + l15;
  if (n < N) {
#pragma unroll
    for (int mt = 0; mt < 2; ++mt)
#pragma unroll
      for (int reg = 0; reg < 4; ++reg) {
        int m = m0 + mt * 16 + quad * 4 + reg;
        if (m >= M) continue;
        if (kslices > 1) {
          atomicAdd(&Cp[(size_t)m * N + n], acc[mt][reg]);
        } else {
          float v = acc[mt][reg];
          if (bias != nullptr) v += bias[m];
          if (relu) v = fmaxf(v, 0.f);
          Cp[(size_t)m * N + n] = v;
        }
      }
  }
}

// ---------------------------------------------------------------------------

extern "C" void kernel_launch(void* const* d_in, const int* in_sizes, int n_in,
                              void* d_out, int out_size, void* d_ws, size_t ws_size,
                              hipStream_t stream) {
  (void)in_sizes; (void)n_in; (void)out_size;

  const float* R0     = (const float*)d_in[0];
  const float* T0     = (const float*)d_in[1];
  const float* inp    = (const float*)d_in[2];
  const float* enc0_w = (const float*)d_in[3];
  const float* enc0_b = (const float*)d_in[4];
  const float* enc1_w = (const float*)d_in[5];
  const float* enc1_b = (const float*)d_in[6];
  const float* off_w[4] = {(const float*)d_in[7], (const float*)d_in[8],
                           (const float*)d_in[9], (const float*)d_in[10]};
  const float* def_w[3] = {(const float*)d_in[11], (const float*)d_in[12],
                           (const float*)d_in[13]};
  const float* w0a = (const float*)d_in[14];
  const float* w0b = (const float*)d_in[15];
  const float* w0c = (const float*)d_in[16];
  const float* w1a = (const float*)d_in[17];
  const float* w1b = (const float*)d_in[18];
  const float* w1c = (const float*)d_in[19];
  const float* wx_w  = (const float*)d_in[20];
  const float* wx_b  = (const float*)d_in[21];
  const float* wxf_w = (const float*)d_in[22];
  const float* wxf_b = (const float*)d_in[23];
  const float* s1w = (const float*)d_in[24];
  const float* s2w = (const float*)d_in[25];
  const float* s3w = (const float*)d_in[26];

  float* ws = (float*)d_ws;
  size_t used = 0;
  auto alloc = [&](size_t n) { float* p = ws + used; used += n; return p; };

  // fixed buffers (FIXED = 23,096,832 floats); variable: batch-4 stsn needs
  // 52,070,400 more floats (~301 MB total) -> runtime-gated.
  const size_t FIXED = 23096832, VAR4 = 52070400;
  const bool big = (FIXED + VAR4) * sizeof(float) <= ws_size;

  float* xy4     = alloc(2359296);
  float* xf      = xy4;
  float* yf      = xy4 + 1179648;
  float* enc4    = alloc(589824);
  float* xenc    = enc4;
  float* yenc    = enc4 + 294912;
  float* offsets4= alloc(165888);
  float* featw4  = alloc(1631232);
  float* featw24 = alloc(1631232);
  float* wb1     = alloc(147456);
  float* wb2     = alloc(36864);
  float* wb3     = alloc(36864);
  float* fw1     = alloc(1024);
  float* fw2     = alloc(1024);
  float* deform4 = alloc(2359296);
  float* sn1     = alloc(1179648);
  float* sn2     = alloc(589824);
  float* sw4     = alloc(9216);
  ushort_t *defw_h[3], *defw_l[3];
  for (int i = 0; i < 3; ++i) {
    defw_h[i] = (ushort_t*)alloc(1179648);
    defw_l[i] = (ushort_t*)alloc(1179648);
  }
  ushort_t *offw_h[4], *offw_l[4];
  for (int i = 0; i < 4; ++i) {
    offw_h[i] = (ushort_t*)alloc(41472);
    offw_l[i] = (ushort_t*)alloc(41472);
  }
  ushort_t* wxf_h = (ushort_t*)alloc(1179648);
  ushort_t* wxf_l = (ushort_t*)alloc(1179648);
  ushort_t* s1w_h = (ushort_t*)alloc(147456);
  ushort_t* s1w_l = (ushort_t*)alloc(147456);
  ushort_t* s2w_h = (ushort_t*)alloc(36864);
  ushort_t* s2w_l = (ushort_t*)alloc(36864);
  ushort_t* w0a_h = (ushort_t*)alloc(144384);
  ushort_t* w0a_l = (ushort_t*)alloc(144384);
  ushort_t* w1a_h = (ushort_t*)alloc(144384);
  ushort_t* w1a_l = (ushort_t*)alloc(144384);
  ushort_t* w0b_h = (ushort_t*)alloc(51200);
  ushort_t* w0b_l = (ushort_t*)alloc(51200);
  ushort_t* w1b_h = (ushort_t*)alloc(51200);
  ushort_t* w1b_l = (ushort_t*)alloc(51200);
  ushort_t* w0c_h = (ushort_t*)alloc(50976);
  ushort_t* w0c_l = (ushort_t*)alloc(50976);
  ushort_t* w1c_h = (ushort_t*)alloc(73728);
  ushort_t* w1c_l = (ushort_t*)alloc(73728);
  ushort_t* e0w_h = (ushort_t*)alloc(8192);
  ushort_t* e0w_l = (ushort_t*)alloc(8192);
  ushort_t* e1w_h = (ushort_t*)alloc(8192);
  ushort_t* e1w_l = (ushort_t*)alloc(8192);
  ushort_t* s3w_h = (ushort_t*)alloc(288);
  ushort_t* s3w_l = (ushort_t*)alloc(288);
  ushort_t* wxad_h = (ushort_t*)alloc(577728);
  ushort_t* wxad_l = (ushort_t*)alloc(577728);
  // variable-size stsn buffers
  float* featA = alloc(big ? 4718592 : 2359296);
  float* featB = alloc(big ? 4718592 : 2359296);
  float* offbN = alloc(big ? 165888 : 82944);
  ushort_t* cols_h = (ushort_t*)alloc(big ? 21233664 : 10616832);
  ushort_t* cols_l = (ushort_t*)alloc(big ? 21233664 : 10616832);
  if (used * sizeof(float) > ws_size) return;

  auto mfma = [&](const ushort_t* Ah, const ushort_t* Al, float* Cmat, int M,
                  int K, int abatch, int relu, int ks, int nb) {
    if (ks > 1)
      hipMemsetAsync(Cmat, 0, (size_t)nb * M * 2304 * sizeof(float), stream);
    dim3 grid(2304 / 64, (M + 127) / 128, nb * ks);
    k_mfma_nt<<<grid, 256, 0, stream>>>(Ah, Al, cols_h, cols_l, Cmat, M, 2304, K,
                                        abatch, relu, ks);
  };
  auto off_conv = [&](const ushort_t* Ah, const ushort_t* Al, const float* src,
                      float* Cmat, int C, int nb) {
    hipMemsetAsync(Cmat, 0, (size_t)nb * 18 * HW * sizeof(float), stream);
    dim3 grid(36, 1, nb * 8);
    k_off_mfma<<<grid, 256, 0, stream>>>(Ah, Al, src, Cmat, 18, C, 8);
  };
  auto im2col = [&](const float* src, const float* off, int C, int nb) {
    dim3 grid(36, C * 9 / 144, nb);
    if (off == nullptr)
      k_im2col2<1><<<grid, 256, 0, stream>>>(src, nullptr, cols_h, cols_l, C);
    else
      k_im2col2<0><<<grid, 256, 0, stream>>>(src, off, cols_h, cols_l, C);
  };
  auto im2col_g = [&](const float* src, int C, int Hin, int Win, int Hout,
                      int Wout, int Ksz, int stridec, int pad, int KP, int nb) {
    dim3 grid((Hout * Wout + 63) / 64, (C + 3) / 4, nb);
    k_im2col_g<<<grid, 256, 0, stream>>>(src, cols_h, cols_l, C, Hin, Win, Hout,
                                         Wout, Ksz, stridec, pad, KP);
  };
  auto gemm_sk = [&](const ushort_t* Ah, const ushort_t* Al, const float* bias,
                     float* Cmat, int M, int N, int KP, int kslices, int relu,
                     int nb) {
    int Nc = ((N + 63) / 64) * 64;
    if (kslices > 1)
      hipMemsetAsync(Cmat, 0, (size_t)nb * M * N * sizeof(float), stream);
    dim3 grid(Nc / 64, (M + 31) / 32, nb * kslices);
    k_gemm_sk<<<grid, 256, 0, stream>>>(Ah, Al, cols_h, cols_l, bias, Cmat, M,
                                        N, Nc, KP, kslices, relu);
  };

  // ---- weight conversions (merged) ----
  k_w2bz3<<<dim3((2359296 + 255) / 256, 1, 3), 256, 0, stream>>>(
      def_w[0], def_w[1], def_w[2], defw_h[0], defw_h[1], defw_h[2],
      defw_l[0], defw_l[1], defw_l[2], 2359296);
  k_w2bz4<<<dim3((82944 + 255) / 256, 1, 4), 256, 0, stream>>>(
      off_w[0], off_w[1], off_w[2], off_w[3], offw_h[0], offw_h[1], offw_h[2],
      offw_h[3], offw_l[0], offw_l[1], offw_l[2], offw_l[3], 82944);
  k_w2b<<<(294912 + 255) / 256, 256, 0, stream>>>(s1w, s1w_h, s1w_l, 294912);
  k_w2b<<<(73728 + 255) / 256, 256, 0, stream>>>(s2w, s2w_h, s2w_l, 73728);
  k_w2b_padz2<<<dim3((64 * 4512 + 255) / 256, 1, 2), 256, 0, stream>>>(
      w0a, w1a, w0a_h, w1a_h, w0a_l, w1a_l, 64, 64, 4425, 4512);
  k_w2b_padz2<<<dim3((64 * 1600 + 255) / 256, 1, 2), 256, 0, stream>>>(
      w0b, w1b, w0b_h, w1b_h, w0b_l, w1b_l, 64, 64, 1600, 1600);
  k_w2b_padz2<<<dim3((256 * 576 + 255) / 256, 1, 2), 256, 0, stream>>>(
      w0c, w1c, w0c_h, w1c_h, w0c_l, w1c_l, 177, 256, 576, 576);
  k_w2b_padz2<<<dim3((64 * 256 + 255) / 256, 1, 2), 256, 0, stream>>>(
      enc0_w, enc1_w, e0w_h, e1w_h, e0w_l, e1w_l, 64, 64, 256, 256);
  k_w2b_pad<<<(576 + 255) / 256, 256, 0, stream>>>(s3w, s3w_h, s3w_l, 1, 576, 576);

  // ---- split + encoders ----
  k_split_xy<<<4608, 256, 0, stream>>>(inp, xf, yf);
  im2col_g(xf, 256, 48, 48, 48, 48, 1, 1, 0, 256, BN);
  gemm_sk(e0w_h, e0w_l, enc0_b, xenc, 64, 2304, 256, 1, 0, BN);
  im2col_g(yf, 256, 48, 48, 48, 48, 1, 1, 0, 256, BN);
  gemm_sk(e1w_h, e1w_l, enc1_b, yenc, 64, 2304, 256, 1, 0, BN);

  // ---- stsn_offset: batch-4 merged chain if scratch allows, else batch-2 ---
  if (big) {
    k_concat512_4<<<(4 * 512 * HW) / 256, 256, 0, stream>>>(xy4, featA);
    float* cur = featA;
    float* nxt = featB;
    for (int i = 0; i < 3; ++i) {
      off_conv(offw_h[i], offw_l[i], cur, offbN, 512, 4);
      im2col(cur, offbN, 512, 4);
      mfma(defw_h[i], defw_l[i], nxt, 512, 4608, 0, 0, 4, 4);
      float* tmp = cur; cur = nxt; nxt = tmp;
    }
    off_conv(offw_h[3], offw_l[3], cur, offsets4, 512, 4);
  } else {
    auto stsn = [&](const float* srcA, const float* srcB, float* offset_out) {
      k_concat512<<<(BN * 512 * HW) / 256, 256, 0, stream>>>(srcA, srcB, featA);
      float* cur = featA;
      float* nxt = featB;
      for (int i = 0; i < 3; ++i) {
        off_conv(offw_h[i], offw_l[i], cur, offbN, 512, BN);
        im2col(cur, offbN, 512, BN);
        mfma(defw_h[i], defw_l[i], nxt, 512, 4608, 0, 0, 4, BN);
        float* tmp = cur; cur = nxt; nxt = tmp;
      }
      off_conv(offw_h[3], offw_l[3], cur, offset_out, 512, BN);
    };
    stsn(xf, yf, offsets4);
    stsn(yf, yf, offsets4 + 2 * 18 * HW);
  }

  // ---- astsn_weight + adaptive deform conv (batch-4) ----
  auto branch = [&](const float* fin, const ushort_t* wah, const ushort_t* wal,
                    const ushort_t* wbh, const ushort_t* wbl,
                    const ushort_t* wch, const ushort_t* wcl, int Mout,
                    float* fwout) {
    im2col_g(fin, 177, 48, 48, 24, 24, 5, 2, 2, 4512, 4);
    gemm_sk(wah, wal, nullptr, wb1, 64, 576, 4512, 8, 0, 4);
    k_relu<<<(4 * 64 * 576 + 255) / 256, 256, 0, stream>>>(wb1, 4 * 64 * 576);
    im2col_g(wb1, 64, 24, 24, 12, 12, 5, 2, 2, 1600, 4);
    gemm_sk(wbh, wbl, nullptr, wb2, 64, 144, 1600, 4, 0, 4);
    k_relu<<<(4 * 64 * 144 + 255) / 256, 256, 0, stream>>>(wb2, 4 * 64 * 144);
    im2col_g(wb2, 64, 12, 12, 6, 6, 3, 2, 1, 576, 4);
    gemm_sk(wch, wcl, nullptr, wb3, Mout, 36, 576, 2, 0, 4);
    k_mean<<<(4 * Mout + 255) / 256, 256, 0, stream>>>(wb3, fwout, 4 * Mout, 36);
  };

  k_correlation4<<<(4 * 49 * HW + 255) / 256, 256, 0, stream>>>(R0, T0, featw4);
  k_pack_enc4<<<(4 * 64 * HW + 255) / 256, 256, 0, stream>>>(enc4, featw4);
  branch(featw4, w0a_h, w0a_l, w0b_h, w0b_l, w0c_h, w0c_l, 177, fw1);
  k_w2b_fw_pad<<<(4 * 177 * 1632 + 255) / 256, 256, 0, stream>>>(
      wx_w, wx_b, fw1, wxad_h, wxad_l, 177, 1593, 1632, 4);
  im2col_g(featw4, 177, 48, 48, 48, 48, 3, 1, 1, 1632, 4);
  mfma(wxad_h, wxad_l, featw24, 177, 1632, 1, 0, 2, 4);
  k_relu<<<(4 * 177 * HW + 255) / 256, 256, 0, stream>>>(featw24, 4 * 177 * HW);
  branch(featw24, w1a_h, w1a_l, w1b_h, w1b_l, w1c_h, w1c_l, 256, fw2);
  k_w2b_fw<<<(4 * 256 * 2304 + 255) / 256, 256, 0, stream>>>(
      wxf_w, wxf_b, fw2, wxf_h, wxf_l, 256, 2304, 4);
  im2col(xy4, offsets4, 256, 4);
  mfma(wxf_h, wxf_l, deform4, 256, 2304, 1, 0, 2, 4);

  // ---- s_net (batch-4) ----
  im2col(deform4, nullptr, 256, 4);
  mfma(s1w_h, s1w_l, sn1, 128, 2304, 0, 0, 4, 4);
  k_relu<<<(4 * 128 * HW + 255) / 256, 256, 0, stream>>>(sn1, 4 * 128 * HW);
  im2col(sn1, nullptr, 128, 4);
  mfma(s2w_h, s2w_l, sn2, 64, 1152, 0, 0, 4, 4);
  k_relu<<<(4 * 64 * HW + 255) / 256, 256, 0, stream>>>(sn2, 4 * 64 * HW);
  im2col_g(sn2, 64, 48, 48, 48, 48, 3, 1, 1, 576, 4);
  gemm_sk(s3w_h, s3w_l, nullptr, sw4, 1, 2304, 576, 1, 1, 4);

  // ---- blend ----
  k_blend<<<4608, 256, 0, stream>>>(deform4, deform4 + 2 * 256 * HW, sw4,
                                    sw4 + 2 * HW, (float*)d_out);
}